// Round 1
// baseline (8054.199 us; speedup 1.0000x reference)
//
#include <hip/hip_runtime.h>
#include <hip/hip_bf16.h>
#include <math.h>

#define B    128
#define CIN  256
#define HIN  8
#define WIN_ 32
#define RH   16
#define RW   64
#define HID  256
#define NC   163
#define T    32
#define L    256
#define CENC 296

__device__ __forceinline__ float bf2f(unsigned short u) {
    unsigned int x = ((unsigned int)u) << 16;
    return __uint_as_float(x);
}
__device__ __forceinline__ unsigned short f2bf(float f) {
    unsigned int x = __float_as_uint(f);
    unsigned int r = (x + 0x7FFFu + ((x >> 16) & 1u)) >> 16;
    return (unsigned short)r;
}
__device__ __forceinline__ float fast_tanh(float x) {
    float e = __expf(2.f * x);
    return 1.f - 2.f * __builtin_amdgcn_rcpf(e + 1.f);
}
__device__ __forceinline__ float fast_sigm(float x) {
    return __builtin_amdgcn_rcpf(1.f + __expf(-x));
}
__device__ __forceinline__ float wave_red_max(float v) {
    #pragma unroll
    for (int o = 32; o > 0; o >>= 1) v = fmaxf(v, __shfl_down(v, o, 64));
    return v;
}
__device__ __forceinline__ float wave_red_sum(float v) {
    #pragma unroll
    for (int o = 32; o > 0; o >>= 1) v += __shfl_down(v, o, 64);
    return v;
}

// ---------------- init: zero h0 and nll accumulators ----------------
__global__ void k_init(float* __restrict__ hbuf, float* __restrict__ nll) {
    int idx = blockIdx.x * 256 + threadIdx.x;
    if (idx < B * HID) hbuf[idx] = 0.f;
    if (blockIdx.x == 0 && threadIdx.x < B) nll[threadIdx.x] = 0.f;
}

// ---------------- bilinear upsample (half-pixel, edge-normalized == clamp) → bf16 ----------------
__global__ void k_upsample(const float* __restrict__ x, unsigned short* __restrict__ xr) {
    int gidx = blockIdx.x * 256 + threadIdx.x;
    int q = gidx & 15;            // x-quad
    int y = (gidx >> 4) & 15;
    int c = (gidx >> 8) & 255;
    int b = gidx >> 16;
    float sy = 0.5f * y - 0.25f;
    int y0 = (y - 1) >> 1;        // floor(sy)
    float wy = sy - (float)y0;
    int y0c = min(max(y0, 0), HIN - 1);
    int y1c = min(max(y0 + 1, 0), HIN - 1);
    const float* r0 = x + ((size_t)(b * CIN + c) * HIN + y0c) * WIN_;
    const float* r1 = x + ((size_t)(b * CIN + c) * HIN + y1c) * WIN_;
    unsigned short o[4];
    #pragma unroll
    for (int rr = 0; rr < 4; rr++) {
        int xx = q * 4 + rr;
        float sx = 0.5f * xx - 0.25f;
        int x0 = (xx - 1) >> 1;
        float wx = sx - (float)x0;
        int x0c = min(max(x0, 0), WIN_ - 1);
        int x1c = min(max(x0 + 1, 0), WIN_ - 1);
        float v = (1.f - wy) * ((1.f - wx) * r0[x0c] + wx * r0[x1c])
                +        wy  * ((1.f - wx) * r1[x0c] + wx * r1[x1c]);
        o[rr] = f2bf(v);
    }
    ushort4 u; u.x = o[0]; u.y = o[1]; u.z = o[2]; u.w = o[3];
    *reinterpret_cast<ushort4*>(xr + (((size_t)(b * CIN + c) * RH + y) * RW + q * 4)) = u;
}

// ---------------- conv3x3 SAME + bias + ReLU + maxpool2x2, writes enc[b][l][c] ----------------
// block = (co4, b), 128 threads: thread = (py 0..7, pxp 0..15) handles 2 pooled px × 4 c_out.
__global__ void __launch_bounds__(128) k_conv(const unsigned short* __restrict__ xr,
                                              const float* __restrict__ conv_w,
                                              const float* __restrict__ conv_b,
                                              float* __restrict__ enc) {
    __shared__ __align__(16) float s[8][18][68];   // 8 cin × (16+2 pad rows) × (64+pad cols), 39.2KB
    const int co0 = blockIdx.x * 4;
    const int b = blockIdx.y;
    const int tid = threadIdx.x;
    const int py = tid >> 4, pxp = tid & 15;
    float acc[4][2][4];
    #pragma unroll
    for (int j = 0; j < 4; j++)
        #pragma unroll
        for (int cy = 0; cy < 2; cy++)
            #pragma unroll
            for (int cx = 0; cx < 4; cx++) acc[j][cy][cx] = 0.f;
    // zero whole tile once (pads stay zero; data region overwritten each chunk)
    for (int idx = tid; idx < 8 * 18 * 68; idx += 128) ((float*)s)[idx] = 0.f;
    const unsigned short* xb = xr + (size_t)b * CIN * RH * RW;
    for (int cc = 0; cc < CIN; cc += 8) {
        __syncthreads();
        #pragma unroll
        for (int it = 0; it < 16; it++) {
            int f = it * 512 + tid * 4;
            int ci = f >> 10, rem = f & 1023, yy = rem >> 6, xx = rem & 63;
            ushort4 u = *reinterpret_cast<const ushort4*>(xb + (size_t)(cc + ci) * (RH * RW) + yy * 64 + xx);
            s[ci][yy + 1][xx + 1] = bf2f(u.x);
            s[ci][yy + 1][xx + 2] = bf2f(u.y);
            s[ci][yy + 1][xx + 3] = bf2f(u.z);
            s[ci][yy + 1][xx + 4] = bf2f(u.w);
        }
        __syncthreads();
        for (int ci = 0; ci < 8; ci++) {
            const int cig = cc + ci;
            float w[4][9];   // wave-uniform → scalar loads
            #pragma unroll
            for (int j = 0; j < 4; j++)
                #pragma unroll
                for (int k = 0; k < 9; k++)
                    w[j][k] = conv_w[(size_t)((co0 + j) * CIN + cig) * 9 + k];
            float win[4][6];
            #pragma unroll
            for (int r = 0; r < 4; r++) {
                const float* row = &s[ci][2 * py + r][4 * pxp];
                float4 a4 = *reinterpret_cast<const float4*>(row);
                float2 b2 = *reinterpret_cast<const float2*>(row + 4);
                win[r][0] = a4.x; win[r][1] = a4.y; win[r][2] = a4.z; win[r][3] = a4.w;
                win[r][4] = b2.x; win[r][5] = b2.y;
            }
            #pragma unroll
            for (int j = 0; j < 4; j++)
                #pragma unroll
                for (int cy = 0; cy < 2; cy++)
                    #pragma unroll
                    for (int cx = 0; cx < 4; cx++) {
                        float a = 0.f;
                        #pragma unroll
                        for (int ky = 0; ky < 3; ky++)
                            #pragma unroll
                            for (int kx = 0; kx < 3; kx++)
                                a += w[j][ky * 3 + kx] * win[cy + ky][cx + kx];
                        acc[j][cy][cx] += a;
                    }
        }
    }
    #pragma unroll
    for (int j = 0; j < 4; j++) {
        float bias = conv_b[co0 + j];
        #pragma unroll
        for (int r = 0; r < 2; r++) {
            int px = 2 * pxp + r;
            float m = fmaxf(fmaxf(acc[j][0][2 * r], acc[j][0][2 * r + 1]),
                            fmaxf(acc[j][1][2 * r], acc[j][1][2 * r + 1]));
            float v = fmaxf(m + bias, 0.f);   // relu(max+bias) == max(relu(+bias))
            enc[(size_t)(b * L + (py * 32 + px)) * CENC + co0 + j] = v;
        }
    }
}

// ---------------- positional channels 256..295 of enc ----------------
__global__ void k_encpos(const float* __restrict__ x_emb, const float* __restrict__ y_emb,
                         float* __restrict__ enc) {
    int b = blockIdx.x, l = threadIdx.x;
    int yl = l >> 5, xl = l & 31;
    float* e = enc + (size_t)(b * L + l) * CENC + 256;
    #pragma unroll
    for (int c = 0; c < 32; c++) e[c] = x_emb[xl * 32 + c];
    #pragma unroll
    for (int c = 0; c < 8; c++) e[32 + c] = y_emb[yl * 8 + c];
}

// ---------------- E[v][h] = emb_dec[v] @ word_w.T + word_b  (vocab table) ----------------
__global__ void __launch_bounds__(256) k_etab(const float* __restrict__ emb_dec,
                                              const float* __restrict__ word_w,
                                              const float* __restrict__ word_b,
                                              float* __restrict__ E) {
    __shared__ float er[NC];
    int row = blockIdx.x, tid = threadIdx.x;
    for (int k = tid; k < NC; k += 256) er[k] = emb_dec[(size_t)row * NC + k];
    __syncthreads();
    float a = word_b[tid];
    for (int k = 0; k < NC; k++) a += er[k] * word_w[(size_t)tid * NC + k];
    E[(size_t)row * HID + tid] = a;
}

// ---------------- transposed weight copies for coalesced matvecs ----------------
__global__ void k_transW(const float* __restrict__ attn_w, const float* __restrict__ out_w,
                         float* __restrict__ wT, float* __restrict__ owT) {
    int k = blockIdx.x, tid = threadIdx.x;
    wT[(size_t)k * HID + tid] = attn_w[(size_t)tid * 552 + k];        // Wh part (cols 0..255)
    if (tid < NC) owT[(size_t)k * NC + tid] = out_w[(size_t)tid * HID + k];
}

// ---------------- ep[b][h][l] = sum_c enc[b][l][c] * attn_w[h][256+c] ----------------
// block = (l-tile 128, h-tile 32, b); thread = 4h × 4l
__global__ void __launch_bounds__(256) k_ep(const float* __restrict__ enc,
                                            const float* __restrict__ attn_w,
                                            float* __restrict__ ep) {
    __shared__ __align__(16) float eS[16][132];
    __shared__ __align__(16) float wS[16][36];
    const int l0 = blockIdx.x * 128;
    const int h0 = blockIdx.y * 32;
    const int b = blockIdx.z;
    const int tid = threadIdx.x;
    const int hh = tid >> 5, ll = tid & 31;
    float acc[4][4];
    #pragma unroll
    for (int s2 = 0; s2 < 4; s2++)
        #pragma unroll
        for (int r = 0; r < 4; r++) acc[s2][r] = 0.f;
    for (int kc = 0; kc < CENC; kc += 16) {
        const int kn = min(16, CENC - kc);
        __syncthreads();
        #pragma unroll
        for (int it = 0; it < 2; it++) {
            int idx = it * 256 + tid;
            int lq = idx >> 2, kq = idx & 3;
            float4 v = make_float4(0.f, 0.f, 0.f, 0.f);
            if (kq * 4 < kn)
                v = *reinterpret_cast<const float4*>(enc + (size_t)(b * L + l0 + lq) * CENC + kc + kq * 4);
            eS[kq * 4 + 0][lq] = v.x; eS[kq * 4 + 1][lq] = v.y;
            eS[kq * 4 + 2][lq] = v.z; eS[kq * 4 + 3][lq] = v.w;
        }
        if (tid < 128) {
            int hq = tid >> 2, kq = tid & 3;
            float4 v = make_float4(0.f, 0.f, 0.f, 0.f);
            if (kq * 4 < kn)
                v = *reinterpret_cast<const float4*>(attn_w + (size_t)(h0 + hq) * 552 + 256 + kc + kq * 4);
            wS[kq * 4 + 0][hq] = v.x; wS[kq * 4 + 1][hq] = v.y;
            wS[kq * 4 + 2][hq] = v.z; wS[kq * 4 + 3][hq] = v.w;
        }
        __syncthreads();
        #pragma unroll
        for (int k = 0; k < 16; k++) {
            float4 e = *reinterpret_cast<const float4*>(&eS[k][ll * 4]);
            float4 w = *reinterpret_cast<const float4*>(&wS[k][hh * 4]);
            float ev[4] = {e.x, e.y, e.z, e.w};
            float wv[4] = {w.x, w.y, w.z, w.w};
            #pragma unroll
            for (int s2 = 0; s2 < 4; s2++)
                #pragma unroll
                for (int r = 0; r < 4; r++) acc[s2][r] += wv[s2] * ev[r];
        }
    }
    #pragma unroll
    for (int s2 = 0; s2 < 4; s2++) {
        float4 o = make_float4(acc[s2][0], acc[s2][1], acc[s2][2], acc[s2][3]);
        *reinterpret_cast<float4*>(ep + (size_t)(b * HID + h0 + hh * 4 + s2) * L + l0 + ll * 4) = o;
    }
}

// ---------------- per-step phase A: nll(prev) + hid_proj + scores + softmax + ctx + rin ----------------
__global__ void __launch_bounds__(256) k_stepA(int t,
        const float* __restrict__ hbuf, const float* __restrict__ ep,
        const float* __restrict__ enc, const float* __restrict__ wT,
        const float* __restrict__ attn_b, const float* __restrict__ attn_v,
        const float* __restrict__ owT, const float* __restrict__ out_b,
        const int* __restrict__ dec_tgt, const int* __restrict__ word_tgt,
        const float* __restrict__ E, float* __restrict__ rin, float* __restrict__ nll) {
    const int b = blockIdx.x, tid = threadIdx.x;
    __shared__ float hS[256], hpS[256], sS[256], vS[256];
    __shared__ float red[4];
    const float* h = hbuf + ((size_t)(t & 1) * B + b) * HID;
    hS[tid] = h[tid];
    vS[tid] = attn_v[tid];
    __syncthreads();
    if (t > 0) {
        float lg = -1e30f;
        if (tid < NC) {
            float a = out_b[tid];
            #pragma unroll 4
            for (int k = 0; k < HID; k++) a += owT[(size_t)k * NC + tid] * hS[k];
            lg = a;
        }
        float m = wave_red_max(lg);
        if ((tid & 63) == 0) red[tid >> 6] = m;
        __syncthreads();
        float M = fmaxf(fmaxf(red[0], red[1]), fmaxf(red[2], red[3]));
        __syncthreads();
        float e = (tid < NC) ? __expf(lg - M) : 0.f;
        float sm = wave_red_sum(e);
        if ((tid & 63) == 0) red[tid >> 6] = sm;
        sS[tid] = lg;
        __syncthreads();
        float S = red[0] + red[1] + red[2] + red[3];
        if (tid == 0) {
            int tgt = word_tgt[b * T + (t - 1)];
            float v = (tgt >= 0) ? (M + __logf(S) - sS[tgt]) : 0.f;
            nll[b] += v;
        }
        __syncthreads();
    }
    {   // hid_proj + attn_b
        float a = attn_b[tid];
        #pragma unroll 4
        for (int k = 0; k < HID; k++) a += wT[(size_t)k * HID + tid] * hS[k];
        hpS[tid] = a;
    }
    __syncthreads();
    {   // scores over l=tid
        const float* epb = ep + (size_t)b * HID * L;
        float sc = 0.f;
        #pragma unroll 4
        for (int hh = 0; hh < HID; hh++)
            sc += vS[hh] * fast_tanh(epb[(size_t)hh * L + tid] + hpS[hh]);
        float m = wave_red_max(sc);
        if ((tid & 63) == 0) red[tid >> 6] = m;
        __syncthreads();
        float M2 = fmaxf(fmaxf(red[0], red[1]), fmaxf(red[2], red[3]));
        __syncthreads();
        float e = __expf(sc - M2);
        float sm = wave_red_sum(e);
        if ((tid & 63) == 0) red[tid >> 6] = sm;
        sS[tid] = e;
        __syncthreads();
        float S2 = red[0] + red[1] + red[2] + red[3];
        float invS = __builtin_amdgcn_rcpf(S2);
        const float* encb = enc + (size_t)b * L * CENC;
        float a0 = 0.f;
        #pragma unroll 4
        for (int l = 0; l < L; l++) a0 += sS[l] * encb[(size_t)l * CENC + tid];
        rin[(size_t)b * 552 + 256 + tid] = a0 * invS;
        if (tid < CENC - 256) {
            int c = 256 + tid;
            float a1 = 0.f;
            #pragma unroll 4
            for (int l = 0; l < L; l++) a1 += sS[l] * encb[(size_t)l * CENC + c];
            rin[(size_t)b * 552 + 256 + c] = a1 * invS;
        }
        int tok = (t == 0) ? 0 : dec_tgt[b * T + (t - 1)];
        rin[(size_t)b * 552 + tid] = E[(size_t)tok * HID + tid];
    }
}

// ---------------- per-step phase B: batched GRU — block = (h-tile 16, b-tile 16) ----------------
__global__ void __launch_bounds__(256) k_stepB(const float* __restrict__ rin,
        const float* __restrict__ hbuf_r, float* __restrict__ hbuf_w,
        const float* __restrict__ wih, const float* __restrict__ bih,
        const float* __restrict__ whh, const float* __restrict__ bhh) {
    __shared__ float rS[16][552];   // 35.3KB
    __shared__ float hSS[16][256];  // 16.4KB
    __shared__ float wS[48][33];    // 6.3KB (pad 33 breaks bank conflicts)
    const int h0 = blockIdx.x * 16;
    const int b0 = blockIdx.y * 16;
    const int tid = threadIdx.x;
    const int i = tid >> 4, j = tid & 15;
    for (int r = 0; r < 16; r++)
        for (int k = tid; k < 552; k += 256) rS[r][k] = rin[(size_t)(b0 + r) * 552 + k];
    for (int r = 0; r < 16; r++) hSS[r][tid] = hbuf_r[(size_t)(b0 + r) * HID + tid];
    float aI0 = bih[h0 + j], aI1 = bih[256 + h0 + j], aI2 = bih[512 + h0 + j];
    float aH0 = bhh[h0 + j], aH1 = bhh[256 + h0 + j], aH2 = bhh[512 + h0 + j];
    for (int kc = 0; kc < 552; kc += 32) {
        int kn = min(32, 552 - kc);
        __syncthreads();
        for (int idx = tid; idx < 48 * 32; idx += 256) {
            int r = idx >> 5, k = idx & 31;
            wS[r][k] = (k < kn) ? wih[(size_t)((r >> 4) * 256 + h0 + (r & 15)) * 552 + kc + k] : 0.f;
        }
        __syncthreads();
        for (int k = 0; k < kn; k++) {
            float rv = rS[i][kc + k];
            aI0 += wS[j][k] * rv; aI1 += wS[16 + j][k] * rv; aI2 += wS[32 + j][k] * rv;
        }
    }
    for (int kc = 0; kc < 256; kc += 32) {
        __syncthreads();
        for (int idx = tid; idx < 48 * 32; idx += 256) {
            int r = idx >> 5, k = idx & 31;
            wS[r][k] = whh[(size_t)((r >> 4) * 256 + h0 + (r & 15)) * HID + kc + k];
        }
        __syncthreads();
        #pragma unroll 8
        for (int k = 0; k < 32; k++) {
            float hv = hSS[i][kc + k];
            aH0 += wS[j][k] * hv; aH1 += wS[16 + j][k] * hv; aH2 += wS[32 + j][k] * hv;
        }
    }
    float r_ = fast_sigm(aI0 + aH0);
    float z_ = fast_sigm(aI1 + aH1);
    float n_ = fast_tanh(aI2 + r_ * aH2);
    float hold = hSS[i][h0 + j];
    hbuf_w[(size_t)(b0 + i) * HID + h0 + j] = (1.f - z_) * n_ + z_ * hold;
}

// ---------------- final step-31 NLL from h_32 (lives in hbuf half 0) ----------------
__global__ void __launch_bounds__(256) k_finalnll(const float* __restrict__ hbuf,
        const float* __restrict__ owT, const float* __restrict__ out_b,
        const int* __restrict__ word_tgt, float* __restrict__ nll) {
    const int b = blockIdx.x, tid = threadIdx.x;
    __shared__ float hS[256], sS[256];
    __shared__ float red[4];
    hS[tid] = hbuf[(size_t)b * HID + tid];
    __syncthreads();
    float lg = -1e30f;
    if (tid < NC) {
        float a = out_b[tid];
        #pragma unroll 4
        for (int k = 0; k < HID; k++) a += owT[(size_t)k * NC + tid] * hS[k];
        lg = a;
    }
    float m = wave_red_max(lg);
    if ((tid & 63) == 0) red[tid >> 6] = m;
    __syncthreads();
    float M = fmaxf(fmaxf(red[0], red[1]), fmaxf(red[2], red[3]));
    __syncthreads();
    float e = (tid < NC) ? __expf(lg - M) : 0.f;
    float sm = wave_red_sum(e);
    if ((tid & 63) == 0) red[tid >> 6] = sm;
    sS[tid] = lg;
    __syncthreads();
    float S = red[0] + red[1] + red[2] + red[3];
    if (tid == 0) {
        int tgt = word_tgt[b * T + (T - 1)];
        float v = (tgt >= 0) ? (M + __logf(S) - sS[tgt]) : 0.f;
        nll[b] += v;
    }
}

// ---------------- loss = 0.2 * mean_b(nll) ----------------
__global__ void k_reduce(const float* __restrict__ nll, float* __restrict__ out) {
    __shared__ float red[2];
    float v = nll[threadIdx.x];
    v = wave_red_sum(v);
    if ((threadIdx.x & 63) == 0) red[threadIdx.x >> 6] = v;
    __syncthreads();
    if (threadIdx.x == 0) out[0] = 0.2f * (red[0] + red[1]) * (1.f / 128.f);
}

extern "C" void kernel_launch(void* const* d_in, const int* in_sizes, int n_in,
                              void* d_out, int out_size, void* d_ws, size_t ws_size,
                              hipStream_t stream) {
    const float* x        = (const float*)d_in[0];
    const int*   dec_tgt  = (const int*)d_in[1];
    const int*   word_tgt = (const int*)d_in[2];
    const float* conv_w   = (const float*)d_in[3];
    const float* conv_b   = (const float*)d_in[4];
    const float* emb_dec  = (const float*)d_in[5];
    const float* word_w   = (const float*)d_in[6];
    const float* word_b   = (const float*)d_in[7];
    const float* attn_w   = (const float*)d_in[8];
    const float* attn_b   = (const float*)d_in[9];
    const float* attn_v   = (const float*)d_in[10];
    const float* gru_wih  = (const float*)d_in[11];
    const float* gru_bih  = (const float*)d_in[12];
    const float* gru_whh  = (const float*)d_in[13];
    const float* gru_bhh  = (const float*)d_in[14];
    const float* out_w    = (const float*)d_in[15];
    const float* out_b    = (const float*)d_in[16];
    const float* x_emb    = (const float*)d_in[17];
    const float* y_emb    = (const float*)d_in[18];

    char* ws = (char*)d_ws;
    size_t off = 0;
    auto alloc = [&](size_t bytes) -> void* {
        void* p = ws + off;
        off = (off + bytes + 255) & ~(size_t)255;
        return p;
    };
    unsigned short* xr = (unsigned short*)alloc((size_t)B * CIN * RH * RW * 2);  // 67MB bf16
    float* enc  = (float*)alloc((size_t)B * L * CENC * 4);                        // 38.8MB
    float* ep   = (float*)alloc((size_t)B * HID * L * 4);                         // 33.6MB
    float* E    = (float*)alloc((size_t)NC * HID * 4);
    float* wT   = (float*)alloc((size_t)HID * HID * 4);
    float* owT  = (float*)alloc((size_t)HID * NC * 4);
    float* rin  = (float*)alloc((size_t)B * 552 * 4);
    float* hbuf = (float*)alloc((size_t)2 * B * HID * 4);
    float* nll  = (float*)alloc((size_t)B * 4);
    float* out  = (float*)d_out;

    hipLaunchKernelGGL(k_init, dim3(128), dim3(256), 0, stream, hbuf, nll);
    hipLaunchKernelGGL(k_upsample, dim3(32768), dim3(256), 0, stream, x, xr);
    hipLaunchKernelGGL(k_conv, dim3(64, 128), dim3(128), 0, stream, xr, conv_w, conv_b, enc);
    hipLaunchKernelGGL(k_encpos, dim3(128), dim3(256), 0, stream, x_emb, y_emb, enc);
    hipLaunchKernelGGL(k_etab, dim3(163), dim3(256), 0, stream, emb_dec, word_w, word_b, E);
    hipLaunchKernelGGL(k_transW, dim3(256), dim3(256), 0, stream, attn_w, out_w, wT, owT);
    hipLaunchKernelGGL(k_ep, dim3(2, 8, 128), dim3(256), 0, stream, enc, attn_w, ep);
    for (int t = 0; t < T; t++) {
        hipLaunchKernelGGL(k_stepA, dim3(128), dim3(256), 0, stream, t,
                           hbuf, ep, enc, wT, attn_b, attn_v, owT, out_b,
                           dec_tgt, word_tgt, E, rin, nll);
        const float* hr = hbuf + (size_t)(t & 1) * B * HID;
        float* hw = hbuf + (size_t)((t + 1) & 1) * B * HID;
        hipLaunchKernelGGL(k_stepB, dim3(16, 8), dim3(256), 0, stream,
                           rin, hr, hw, gru_wih, gru_bih, gru_whh, gru_bhh);
    }
    hipLaunchKernelGGL(k_finalnll, dim3(128), dim3(256), 0, stream, hbuf, owT, out_b, word_tgt, nll);
    hipLaunchKernelGGL(k_reduce, dim3(1), dim3(128), 0, stream, nll, out);
}

// Round 2
// 5647.606 us; speedup vs baseline: 1.4261x; 1.4261x over previous
//
#include <hip/hip_runtime.h>
#include <hip/hip_bf16.h>
#include <math.h>

#define B    128
#define CIN  256
#define HIN  8
#define WIN_ 32
#define RH   16
#define RW   64
#define HID  256
#define NC   163
#define T    32
#define L    256
#define CENC 296

__device__ __forceinline__ float bf2f(unsigned short u) {
    unsigned int x = ((unsigned int)u) << 16;
    return __uint_as_float(x);
}
__device__ __forceinline__ unsigned short f2bf(float f) {
    unsigned int x = __float_as_uint(f);
    unsigned int r = (x + 0x7FFFu + ((x >> 16) & 1u)) >> 16;
    return (unsigned short)r;
}
__device__ __forceinline__ float fast_tanh(float x) {
    float e = __expf(2.f * x);
    return 1.f - 2.f * __builtin_amdgcn_rcpf(e + 1.f);
}
__device__ __forceinline__ float fast_sigm(float x) {
    return __builtin_amdgcn_rcpf(1.f + __expf(-x));
}
__device__ __forceinline__ float wave_red_max(float v) {
    #pragma unroll
    for (int o = 32; o > 0; o >>= 1) v = fmaxf(v, __shfl_down(v, o, 64));
    return v;
}
__device__ __forceinline__ float wave_red_sum(float v) {
    #pragma unroll
    for (int o = 32; o > 0; o >>= 1) v += __shfl_down(v, o, 64);
    return v;
}

// ---------------- init: zero h0 and nll accumulators ----------------
__global__ void k_init(float* __restrict__ hbuf, float* __restrict__ nll) {
    int idx = blockIdx.x * 256 + threadIdx.x;
    if (idx < B * HID) hbuf[idx] = 0.f;
    if (blockIdx.x == 0 && threadIdx.x < B) nll[threadIdx.x] = 0.f;
}

// ---------------- bilinear upsample (half-pixel) → bf16 ----------------
__global__ void k_upsample(const float* __restrict__ x, unsigned short* __restrict__ xr) {
    int gidx = blockIdx.x * 256 + threadIdx.x;
    int q = gidx & 15;
    int y = (gidx >> 4) & 15;
    int c = (gidx >> 8) & 255;
    int b = gidx >> 16;
    float sy = 0.5f * y - 0.25f;
    int y0 = (y - 1) >> 1;
    float wy = sy - (float)y0;
    int y0c = min(max(y0, 0), HIN - 1);
    int y1c = min(max(y0 + 1, 0), HIN - 1);
    const float* r0 = x + ((size_t)(b * CIN + c) * HIN + y0c) * WIN_;
    const float* r1 = x + ((size_t)(b * CIN + c) * HIN + y1c) * WIN_;
    unsigned short o[4];
    #pragma unroll
    for (int rr = 0; rr < 4; rr++) {
        int xx = q * 4 + rr;
        float sx = 0.5f * xx - 0.25f;
        int x0 = (xx - 1) >> 1;
        float wx = sx - (float)x0;
        int x0c = min(max(x0, 0), WIN_ - 1);
        int x1c = min(max(x0 + 1, 0), WIN_ - 1);
        float v = (1.f - wy) * ((1.f - wx) * r0[x0c] + wx * r0[x1c])
                +        wy  * ((1.f - wx) * r1[x0c] + wx * r1[x1c]);
        o[rr] = f2bf(v);
    }
    ushort4 u; u.x = o[0]; u.y = o[1]; u.z = o[2]; u.w = o[3];
    *reinterpret_cast<ushort4*>(xr + (((size_t)(b * CIN + c) * RH + y) * RW + q * 4)) = u;
}

// ---------------- conv3x3 SAME + bias + ReLU + maxpool2x2 → enc_bf[b][l][c] (bf16) ----------------
__global__ void __launch_bounds__(128) k_conv(const unsigned short* __restrict__ xr,
                                              const float* __restrict__ conv_w,
                                              const float* __restrict__ conv_b,
                                              unsigned short* __restrict__ enc_bf) {
    __shared__ __align__(16) float s[8][18][68];
    const int co0 = blockIdx.x * 4;
    const int b = blockIdx.y;
    const int tid = threadIdx.x;
    const int py = tid >> 4, pxp = tid & 15;
    float acc[4][2][4];
    #pragma unroll
    for (int j = 0; j < 4; j++)
        #pragma unroll
        for (int cy = 0; cy < 2; cy++)
            #pragma unroll
            for (int cx = 0; cx < 4; cx++) acc[j][cy][cx] = 0.f;
    for (int idx = tid; idx < 8 * 18 * 68; idx += 128) ((float*)s)[idx] = 0.f;
    const unsigned short* xb = xr + (size_t)b * CIN * RH * RW;
    for (int cc = 0; cc < CIN; cc += 8) {
        __syncthreads();
        #pragma unroll
        for (int it = 0; it < 16; it++) {
            int f = it * 512 + tid * 4;
            int ci = f >> 10, rem = f & 1023, yy = rem >> 6, xx = rem & 63;
            ushort4 u = *reinterpret_cast<const ushort4*>(xb + (size_t)(cc + ci) * (RH * RW) + yy * 64 + xx);
            s[ci][yy + 1][xx + 1] = bf2f(u.x);
            s[ci][yy + 1][xx + 2] = bf2f(u.y);
            s[ci][yy + 1][xx + 3] = bf2f(u.z);
            s[ci][yy + 1][xx + 4] = bf2f(u.w);
        }
        __syncthreads();
        for (int ci = 0; ci < 8; ci++) {
            const int cig = cc + ci;
            float w[4][9];
            #pragma unroll
            for (int j = 0; j < 4; j++)
                #pragma unroll
                for (int k = 0; k < 9; k++)
                    w[j][k] = conv_w[(size_t)((co0 + j) * CIN + cig) * 9 + k];
            float win[4][6];
            #pragma unroll
            for (int r = 0; r < 4; r++) {
                const float* row = &s[ci][2 * py + r][4 * pxp];
                float4 a4 = *reinterpret_cast<const float4*>(row);
                float2 b2 = *reinterpret_cast<const float2*>(row + 4);
                win[r][0] = a4.x; win[r][1] = a4.y; win[r][2] = a4.z; win[r][3] = a4.w;
                win[r][4] = b2.x; win[r][5] = b2.y;
            }
            #pragma unroll
            for (int j = 0; j < 4; j++)
                #pragma unroll
                for (int cy = 0; cy < 2; cy++)
                    #pragma unroll
                    for (int cx = 0; cx < 4; cx++) {
                        float a = 0.f;
                        #pragma unroll
                        for (int ky = 0; ky < 3; ky++)
                            #pragma unroll
                            for (int kx = 0; kx < 3; kx++)
                                a += w[j][ky * 3 + kx] * win[cy + ky][cx + kx];
                        acc[j][cy][cx] += a;
                    }
        }
    }
    #pragma unroll
    for (int j = 0; j < 4; j++) {
        float bias = conv_b[co0 + j];
        #pragma unroll
        for (int r = 0; r < 2; r++) {
            int px = 2 * pxp + r;
            float m = fmaxf(fmaxf(acc[j][0][2 * r], acc[j][0][2 * r + 1]),
                            fmaxf(acc[j][1][2 * r], acc[j][1][2 * r + 1]));
            float v = fmaxf(m + bias, 0.f);
            enc_bf[(size_t)(b * L + (py * 32 + px)) * CENC + co0 + j] = f2bf(v);
        }
    }
}

// ---------------- positional channels 256..295 (bf16) + pos2[l][40] fp32 table ----------------
__global__ void k_encpos(const float* __restrict__ x_emb, const float* __restrict__ y_emb,
                         unsigned short* __restrict__ enc_bf, float* __restrict__ pos2) {
    int b = blockIdx.x, l = threadIdx.x;
    int yl = l >> 5, xl = l & 31;
    unsigned short* e = enc_bf + (size_t)(b * L + l) * CENC + 256;
    #pragma unroll
    for (int c = 0; c < 32; c++) e[c] = f2bf(x_emb[xl * 32 + c]);
    #pragma unroll
    for (int c = 0; c < 8; c++) e[32 + c] = f2bf(y_emb[yl * 8 + c]);
    if (b == 0) {
        #pragma unroll
        for (int c = 0; c < 40; c++)
            pos2[l * 40 + c] = (c < 32) ? x_emb[xl * 32 + c] : y_emb[yl * 8 + (c - 32)];
    }
}

// ---------------- E[v][h] = emb_dec[v] @ word_w.T + word_b ----------------
__global__ void __launch_bounds__(256) k_etab(const float* __restrict__ emb_dec,
                                              const float* __restrict__ word_w,
                                              const float* __restrict__ word_b,
                                              float* __restrict__ E) {
    __shared__ float er[NC];
    int row = blockIdx.x, tid = threadIdx.x;
    for (int k = tid; k < NC; k += 256) er[k] = emb_dec[(size_t)row * NC + k];
    __syncthreads();
    float a = word_b[tid];
    for (int k = 0; k < NC; k++) a += er[k] * word_w[(size_t)tid * NC + k];
    E[(size_t)row * HID + tid] = a;
}

// ---------------- transposed weight copies (bf16 for steps, fp32 owT for finalnll) ----------------
__global__ void k_transW(const float* __restrict__ attn_w, const float* __restrict__ out_w,
                         unsigned short* __restrict__ wT_bf, unsigned short* __restrict__ owT_bf,
                         float* __restrict__ owT) {
    int k = blockIdx.x, tid = threadIdx.x;
    wT_bf[(size_t)k * HID + tid] = f2bf(attn_w[(size_t)tid * 552 + k]);
    if (tid < NC) {
        float v = out_w[(size_t)tid * HID + k];
        owT_bf[(size_t)k * NC + tid] = f2bf(v);
        owT[(size_t)k * NC + tid] = v;
    }
}

// ---------------- ep_bf[b][h][l] = sum_c enc[b][l][c] * attn_w[h][256+c] (bf16 out) ----------------
__global__ void __launch_bounds__(256) k_ep(const unsigned short* __restrict__ enc_bf,
                                            const float* __restrict__ attn_w,
                                            unsigned short* __restrict__ ep_bf) {
    __shared__ __align__(16) float eS[16][132];
    __shared__ __align__(16) float wS[16][36];
    const int l0 = blockIdx.x * 128;
    const int h0 = blockIdx.y * 32;
    const int b = blockIdx.z;
    const int tid = threadIdx.x;
    const int hh = tid >> 5, ll = tid & 31;
    float acc[4][4];
    #pragma unroll
    for (int s2 = 0; s2 < 4; s2++)
        #pragma unroll
        for (int r = 0; r < 4; r++) acc[s2][r] = 0.f;
    for (int kc = 0; kc < CENC; kc += 16) {
        const int kn = min(16, CENC - kc);
        __syncthreads();
        #pragma unroll
        for (int it = 0; it < 2; it++) {
            int idx = it * 256 + tid;
            int lq = idx >> 2, kq = idx & 3;
            float v0 = 0.f, v1 = 0.f, v2 = 0.f, v3 = 0.f;
            if (kq * 4 < kn) {
                ushort4 u = *reinterpret_cast<const ushort4*>(
                    enc_bf + (size_t)(b * L + l0 + lq) * CENC + kc + kq * 4);
                v0 = bf2f(u.x); v1 = bf2f(u.y); v2 = bf2f(u.z); v3 = bf2f(u.w);
            }
            eS[kq * 4 + 0][lq] = v0; eS[kq * 4 + 1][lq] = v1;
            eS[kq * 4 + 2][lq] = v2; eS[kq * 4 + 3][lq] = v3;
        }
        if (tid < 128) {
            int hq = tid >> 2, kq = tid & 3;
            float4 v = make_float4(0.f, 0.f, 0.f, 0.f);
            if (kq * 4 < kn)
                v = *reinterpret_cast<const float4*>(attn_w + (size_t)(h0 + hq) * 552 + 256 + kc + kq * 4);
            wS[kq * 4 + 0][hq] = v.x; wS[kq * 4 + 1][hq] = v.y;
            wS[kq * 4 + 2][hq] = v.z; wS[kq * 4 + 3][hq] = v.w;
        }
        __syncthreads();
        #pragma unroll
        for (int k = 0; k < 16; k++) {
            float4 e = *reinterpret_cast<const float4*>(&eS[k][ll * 4]);
            float4 w = *reinterpret_cast<const float4*>(&wS[k][hh * 4]);
            float ev[4] = {e.x, e.y, e.z, e.w};
            float wv[4] = {w.x, w.y, w.z, w.w};
            #pragma unroll
            for (int s2 = 0; s2 < 4; s2++)
                #pragma unroll
                for (int r = 0; r < 4; r++) acc[s2][r] += wv[s2] * ev[r];
        }
    }
    #pragma unroll
    for (int s2 = 0; s2 < 4; s2++) {
        ushort4 o;
        o.x = f2bf(acc[s2][0]); o.y = f2bf(acc[s2][1]);
        o.z = f2bf(acc[s2][2]); o.w = f2bf(acc[s2][3]);
        *reinterpret_cast<ushort4*>(ep_bf + (size_t)(b * HID + h0 + hh * 4 + s2) * L + l0 + ll * 4) = o;
    }
}

// ---------------- per-step phase A: 1024 threads, K-split x4 ----------------
// thread = (o = tid&255 : output index, q = tid>>8 : K-chunk)
__global__ void __launch_bounds__(1024) k_stepA(int t,
        const float* __restrict__ hbuf, const unsigned short* __restrict__ ep_bf,
        const unsigned short* __restrict__ enc_bf, const unsigned short* __restrict__ wT_bf,
        const float* __restrict__ attn_b, const float* __restrict__ attn_v,
        const unsigned short* __restrict__ owT_bf, const float* __restrict__ out_b,
        const int* __restrict__ dec_tgt, const int* __restrict__ word_tgt,
        const float* __restrict__ E, const float* __restrict__ pos2,
        float* __restrict__ rin, float* __restrict__ nll) {
    const int b = blockIdx.x, tid = threadIdx.x;
    const int o = tid & 255, q = tid >> 8;
    __shared__ float hS[256], hpS[256], sS[256], vS[256];
    __shared__ float part[4][256];
    __shared__ float part2[16][40];
    __shared__ float red[16];
    if (tid < 256) {
        hS[tid] = hbuf[((size_t)(t & 1) * B + b) * HID + tid];
        vS[tid] = attn_v[tid];
    }
    __syncthreads();

    // ---- phase 1 (t>0): logits of h_t vs word_targets[t-1] ----
    if (t > 0) {
        float pl = 0.f;
        if (o < NC) {
            const unsigned short* wc = owT_bf + (size_t)(q * 64) * NC + o;
            #pragma unroll 4
            for (int k = 0; k < 64; k++) pl += bf2f(wc[(size_t)k * NC]) * hS[q * 64 + k];
        }
        part[q][o] = pl;
        __syncthreads();
        float lg = -1e30f;
        if (tid < 256) {
            if (tid < NC)
                lg = out_b[tid] + part[0][tid] + part[1][tid] + part[2][tid] + part[3][tid];
            float m = wave_red_max(lg);
            if ((tid & 63) == 0) red[tid >> 6] = m;
        }
        __syncthreads();
        float M = fmaxf(fmaxf(red[0], red[1]), fmaxf(red[2], red[3]));
        if (tid < 256) {
            sS[tid] = lg;
            float e = (tid < NC) ? __expf(lg - M) : 0.f;
            float sm = wave_red_sum(e);
            if ((tid & 63) == 0) red[8 + (tid >> 6)] = sm;
        }
        __syncthreads();
        if (tid == 0) {
            float S = red[8] + red[9] + red[10] + red[11];
            int tgt = word_tgt[b * T + (t - 1)];
            if (tgt >= 0) nll[b] += M + __logf(S) - sS[tgt];
        }
        __syncthreads();
    }

    // ---- phase 2: hp = h @ Wh^T + attn_b ----
    {
        float ph = 0.f;
        const unsigned short* wc = wT_bf + (size_t)(q * 64) * HID + o;
        #pragma unroll 4
        for (int k = 0; k < 64; k++) ph += bf2f(wc[(size_t)k * HID]) * hS[q * 64 + k];
        part[q][o] = ph;
    }
    __syncthreads();
    if (tid < 256)
        hpS[tid] = attn_b[tid] + part[0][tid] + part[1][tid] + part[2][tid] + part[3][tid];
    __syncthreads();

    // ---- phase 3: scores + softmax ----
    {
        float ps = 0.f;
        const unsigned short* epq = ep_bf + ((size_t)(b * HID) + q * 64) * L + o;
        #pragma unroll 4
        for (int hh = 0; hh < 64; hh++)
            ps += vS[q * 64 + hh] * fast_tanh(bf2f(epq[(size_t)hh * L]) + hpS[q * 64 + hh]);
        part[q][o] = ps;
    }
    __syncthreads();
    float sc = -1e30f;
    if (tid < 256) {
        sc = part[0][tid] + part[1][tid] + part[2][tid] + part[3][tid];
        float m = wave_red_max(sc);
        if ((tid & 63) == 0) red[tid >> 6] = m;
    }
    __syncthreads();
    float M2 = fmaxf(fmaxf(red[0], red[1]), fmaxf(red[2], red[3]));
    if (tid < 256) {
        float e2 = __expf(sc - M2);
        sS[tid] = e2;
        float sm = wave_red_sum(e2);
        if ((tid & 63) == 0) red[8 + (tid >> 6)] = sm;
    }
    __syncthreads();
    float invS = __builtin_amdgcn_rcpf(red[8] + red[9] + red[10] + red[11]);

    // ---- phase 4: ctx (channels 0..255) ----
    {
        float pc = 0.f;
        const unsigned short* eb = enc_bf + ((size_t)(b * L) + q * 64) * CENC + o;
        #pragma unroll 4
        for (int l = 0; l < 64; l++) pc += sS[q * 64 + l] * bf2f(eb[(size_t)l * CENC]);
        part[q][o] = pc;
    }
    __syncthreads();
    if (tid < 256)
        rin[(size_t)b * 552 + 256 + tid] =
            (part[0][tid] + part[1][tid] + part[2][tid] + part[3][tid]) * invS;

    // ---- phase 4b: ctx positional channels 256..295 (b-independent pos2 table) ----
    {
        int c2 = tid & 63, q2 = tid >> 6;   // q2 in 0..15, 16 l's each
        float pc2 = 0.f;
        if (c2 < 40) {
            #pragma unroll 4
            for (int l = 0; l < 16; l++)
                pc2 += sS[q2 * 16 + l] * pos2[(q2 * 16 + l) * 40 + c2];
            part2[q2][c2] = pc2;
        }
    }
    __syncthreads();
    if (tid < 40) {
        float s = 0.f;
        #pragma unroll
        for (int j = 0; j < 16; j++) s += part2[j][tid];
        rin[(size_t)b * 552 + 512 + tid] = s * invS;
    }

    // ---- phase 5: word embedding gather ----
    if (tid < 256) {
        int tok = (t == 0) ? 0 : dec_tgt[b * T + (t - 1)];
        rin[(size_t)b * 552 + tid] = E[(size_t)tok * HID + tid];
    }
}

// ---------------- per-step phase B: batched GRU ----------------
__global__ void __launch_bounds__(256) k_stepB(const float* __restrict__ rin,
        const float* __restrict__ hbuf_r, float* __restrict__ hbuf_w,
        const float* __restrict__ wih, const float* __restrict__ bih,
        const float* __restrict__ whh, const float* __restrict__ bhh) {
    __shared__ float rS[16][552];
    __shared__ float hSS[16][256];
    __shared__ float wS[48][33];
    const int h0 = blockIdx.x * 16;
    const int b0 = blockIdx.y * 16;
    const int tid = threadIdx.x;
    const int i = tid >> 4, j = tid & 15;
    for (int r = 0; r < 16; r++)
        for (int k = tid; k < 552; k += 256) rS[r][k] = rin[(size_t)(b0 + r) * 552 + k];
    for (int r = 0; r < 16; r++) hSS[r][tid] = hbuf_r[(size_t)(b0 + r) * HID + tid];
    float aI0 = bih[h0 + j], aI1 = bih[256 + h0 + j], aI2 = bih[512 + h0 + j];
    float aH0 = bhh[h0 + j], aH1 = bhh[256 + h0 + j], aH2 = bhh[512 + h0 + j];
    for (int kc = 0; kc < 552; kc += 32) {
        int kn = min(32, 552 - kc);
        __syncthreads();
        for (int idx = tid; idx < 48 * 32; idx += 256) {
            int r = idx >> 5, k = idx & 31;
            wS[r][k] = (k < kn) ? wih[(size_t)((r >> 4) * 256 + h0 + (r & 15)) * 552 + kc + k] : 0.f;
        }
        __syncthreads();
        for (int k = 0; k < kn; k++) {
            float rv = rS[i][kc + k];
            aI0 += wS[j][k] * rv; aI1 += wS[16 + j][k] * rv; aI2 += wS[32 + j][k] * rv;
        }
    }
    for (int kc = 0; kc < 256; kc += 32) {
        __syncthreads();
        for (int idx = tid; idx < 48 * 32; idx += 256) {
            int r = idx >> 5, k = idx & 31;
            wS[r][k] = whh[(size_t)((r >> 4) * 256 + h0 + (r & 15)) * HID + kc + k];
        }
        __syncthreads();
        #pragma unroll 8
        for (int k = 0; k < 32; k++) {
            float hv = hSS[i][kc + k];
            aH0 += wS[j][k] * hv; aH1 += wS[16 + j][k] * hv; aH2 += wS[32 + j][k] * hv;
        }
    }
    float r_ = fast_sigm(aI0 + aH0);
    float z_ = fast_sigm(aI1 + aH1);
    float n_ = fast_tanh(aI2 + r_ * aH2);
    float hold = hSS[i][h0 + j];
    hbuf_w[(size_t)(b0 + i) * HID + h0 + j] = (1.f - z_) * n_ + z_ * hold;
}

// ---------------- final step-31 NLL from h_32 ----------------
__global__ void __launch_bounds__(256) k_finalnll(const float* __restrict__ hbuf,
        const float* __restrict__ owT, const float* __restrict__ out_b,
        const int* __restrict__ word_tgt, float* __restrict__ nll) {
    const int b = blockIdx.x, tid = threadIdx.x;
    __shared__ float hS[256], sS[256];
    __shared__ float red[8];
    hS[tid] = hbuf[(size_t)b * HID + tid];
    __syncthreads();
    float lg = -1e30f;
    if (tid < NC) {
        float a = out_b[tid];
        #pragma unroll 4
        for (int k = 0; k < HID; k++) a += owT[(size_t)k * NC + tid] * hS[k];
        lg = a;
    }
    float m = wave_red_max(lg);
    if ((tid & 63) == 0) red[tid >> 6] = m;
    __syncthreads();
    float M = fmaxf(fmaxf(red[0], red[1]), fmaxf(red[2], red[3]));
    __syncthreads();
    float e = (tid < NC) ? __expf(lg - M) : 0.f;
    float sm = wave_red_sum(e);
    if ((tid & 63) == 0) red[tid >> 6] = sm;
    sS[tid] = lg;
    __syncthreads();
    float S = red[0] + red[1] + red[2] + red[3];
    if (tid == 0) {
        int tgt = word_tgt[b * T + (T - 1)];
        if (tgt >= 0) nll[b] += M + __logf(S) - sS[tgt];
    }
}

// ---------------- loss = 0.2 * mean_b(nll) ----------------
__global__ void k_reduce(const float* __restrict__ nll, float* __restrict__ out) {
    __shared__ float red[2];
    float v = nll[threadIdx.x];
    v = wave_red_sum(v);
    if ((threadIdx.x & 63) == 0) red[threadIdx.x >> 6] = v;
    __syncthreads();
    if (threadIdx.x == 0) out[0] = 0.2f * (red[0] + red[1]) * (1.f / 128.f);
}

extern "C" void kernel_launch(void* const* d_in, const int* in_sizes, int n_in,
                              void* d_out, int out_size, void* d_ws, size_t ws_size,
                              hipStream_t stream) {
    const float* x        = (const float*)d_in[0];
    const int*   dec_tgt  = (const int*)d_in[1];
    const int*   word_tgt = (const int*)d_in[2];
    const float* conv_w   = (const float*)d_in[3];
    const float* conv_b   = (const float*)d_in[4];
    const float* emb_dec  = (const float*)d_in[5];
    const float* word_w   = (const float*)d_in[6];
    const float* word_b   = (const float*)d_in[7];
    const float* attn_w   = (const float*)d_in[8];
    const float* attn_b   = (const float*)d_in[9];
    const float* attn_v   = (const float*)d_in[10];
    const float* gru_wih  = (const float*)d_in[11];
    const float* gru_bih  = (const float*)d_in[12];
    const float* gru_whh  = (const float*)d_in[13];
    const float* gru_bhh  = (const float*)d_in[14];
    const float* out_w    = (const float*)d_in[15];
    const float* out_b    = (const float*)d_in[16];
    const float* x_emb    = (const float*)d_in[17];
    const float* y_emb    = (const float*)d_in[18];

    char* ws = (char*)d_ws;
    size_t off = 0;
    auto alloc = [&](size_t bytes) -> void* {
        void* p = ws + off;
        off = (off + bytes + 255) & ~(size_t)255;
        return p;
    };
    unsigned short* xr     = (unsigned short*)alloc((size_t)B * CIN * RH * RW * 2);  // 67MB
    unsigned short* enc_bf = (unsigned short*)alloc((size_t)B * L * CENC * 2);        // 19.4MB
    unsigned short* ep_bf  = (unsigned short*)alloc((size_t)B * HID * L * 2);         // 16.8MB
    float* E      = (float*)alloc((size_t)NC * HID * 4);
    float* owT    = (float*)alloc((size_t)HID * NC * 4);
    unsigned short* wT_bf  = (unsigned short*)alloc((size_t)HID * HID * 2);
    unsigned short* owT_bf = (unsigned short*)alloc((size_t)HID * NC * 2);
    float* pos2   = (float*)alloc((size_t)L * 40 * 4);
    float* rin    = (float*)alloc((size_t)B * 552 * 4);
    float* hbuf   = (float*)alloc((size_t)2 * B * HID * 4);
    float* nll    = (float*)alloc((size_t)B * 4);
    float* out    = (float*)d_out;

    hipLaunchKernelGGL(k_init, dim3(128), dim3(256), 0, stream, hbuf, nll);
    hipLaunchKernelGGL(k_upsample, dim3(32768), dim3(256), 0, stream, x, xr);
    hipLaunchKernelGGL(k_conv, dim3(64, 128), dim3(128), 0, stream, xr, conv_w, conv_b, enc_bf);
    hipLaunchKernelGGL(k_encpos, dim3(128), dim3(256), 0, stream, x_emb, y_emb, enc_bf, pos2);
    hipLaunchKernelGGL(k_etab, dim3(163), dim3(256), 0, stream, emb_dec, word_w, word_b, E);
    hipLaunchKernelGGL(k_transW, dim3(256), dim3(256), 0, stream, attn_w, out_w, wT_bf, owT_bf, owT);
    hipLaunchKernelGGL(k_ep, dim3(2, 8, 128), dim3(256), 0, stream, enc_bf, attn_w, ep_bf);
    for (int t = 0; t < T; t++) {
        hipLaunchKernelGGL(k_stepA, dim3(128), dim3(1024), 0, stream, t,
                           hbuf, ep_bf, enc_bf, wT_bf, attn_b, attn_v, owT_bf, out_b,
                           dec_tgt, word_tgt, E, pos2, rin, nll);
        const float* hr = hbuf + (size_t)(t & 1) * B * HID;
        float* hw = hbuf + (size_t)((t + 1) & 1) * B * HID;
        hipLaunchKernelGGL(k_stepB, dim3(16, 8), dim3(256), 0, stream,
                           rin, hr, hw, gru_wih, gru_bih, gru_whh, gru_bhh);
    }
    hipLaunchKernelGGL(k_finalnll, dim3(128), dim3(256), 0, stream, hbuf, owT, out_b, word_tgt, nll);
    hipLaunchKernelGGL(k_reduce, dim3(1), dim3(128), 0, stream, nll, out);
}

// Round 3
// 3816.595 us; speedup vs baseline: 2.1103x; 1.4797x over previous
//
#include <hip/hip_runtime.h>
#include <hip/hip_bf16.h>
#include <math.h>

#define B    128
#define CIN  256
#define HIN  8
#define WIN_ 32
#define RH   16
#define RW   64
#define HID  256
#define NC   163
#define T    32
#define L    256
#define CENC 296

typedef __attribute__((ext_vector_type(8))) short short8;
typedef __attribute__((ext_vector_type(8))) unsigned short u16x8;
typedef __attribute__((ext_vector_type(4))) float f32x4;

__device__ __forceinline__ float bf2f(unsigned short u) {
    unsigned int x = ((unsigned int)u) << 16;
    return __uint_as_float(x);
}
__device__ __forceinline__ unsigned short f2bf(float f) {
    unsigned int x = __float_as_uint(f);
    unsigned int r = (x + 0x7FFFu + ((x >> 16) & 1u)) >> 16;
    return (unsigned short)r;
}
__device__ __forceinline__ float fast_tanh(float x) {
    float e = __expf(2.f * x);
    return 1.f - 2.f * __builtin_amdgcn_rcpf(e + 1.f);
}
__device__ __forceinline__ float fast_sigm(float x) {
    return __builtin_amdgcn_rcpf(1.f + __expf(-x));
}
__device__ __forceinline__ float wave_red_max(float v) {
    #pragma unroll
    for (int o = 32; o > 0; o >>= 1) v = fmaxf(v, __shfl_down(v, o, 64));
    return v;
}
__device__ __forceinline__ float wave_red_sum(float v) {
    #pragma unroll
    for (int o = 32; o > 0; o >>= 1) v += __shfl_down(v, o, 64);
    return v;
}

// ---------------- init ----------------
__global__ void k_init(float* __restrict__ hbuf, float* __restrict__ nll) {
    int idx = blockIdx.x * 256 + threadIdx.x;
    if (idx < B * HID) hbuf[idx] = 0.f;
    if (blockIdx.x == 0 && threadIdx.x < B) nll[threadIdx.x] = 0.f;
}

// ---------------- bilinear upsample fused with transpose → Xt[b][y][x][ci] bf16 ----------------
// block = (y, b), 256 threads = (x 64, c-group 4); LDS-staged source rows, 4 c-chunks of 64.
__global__ void __launch_bounds__(256) k_upsxt(const float* __restrict__ x,
                                               unsigned short* __restrict__ Xt) {
    __shared__ __align__(16) float sf[64 * 2 * 32];   // [c 64][row 2][xs 32] = 16KB
    const int y = blockIdx.x;
    const int b = blockIdx.y;
    const int tid = threadIdx.x;
    float sy = 0.5f * y - 0.25f;
    int yq0 = (y - 1) >> 1;
    float wy = sy - (float)yq0;
    int y0c = min(max(yq0, 0), HIN - 1);
    int y1c = min(max(yq0 + 1, 0), HIN - 1);
    const int xo = tid & 63;
    const int cj = tid >> 6;
    float sx = 0.5f * xo - 0.25f;
    int xq0 = (xo - 1) >> 1;
    float wx = sx - (float)xq0;
    int x0c = min(max(xq0, 0), WIN_ - 1);
    int x1c = min(max(xq0 + 1, 0), WIN_ - 1);
    for (int cc = 0; cc < 4; cc++) {
        __syncthreads();
        #pragma unroll
        for (int i = 0; i < 4; i++) {
            int idx = tid * 4 + i;           // 0..1023 float4 slots
            int c = idx >> 4;                // 0..63
            int rowh = (idx >> 3) & 1;
            int part = idx & 7;
            int ysrc = rowh ? y1c : y0c;
            float4 v = *reinterpret_cast<const float4*>(
                x + ((size_t)(b * CIN + cc * 64 + c) * HIN + ysrc) * WIN_ + part * 4);
            *reinterpret_cast<float4*>(sf + ((c * 2 + rowh) * 32 + part * 4)) = v;
        }
        __syncthreads();
        unsigned short ov[16];
        #pragma unroll
        for (int j = 0; j < 16; j++) {
            int c = cj * 16 + j;
            const float* r0 = sf + (c * 2 + 0) * 32;
            const float* r1 = sf + (c * 2 + 1) * 32;
            float v = (1.f - wy) * ((1.f - wx) * r0[x0c] + wx * r0[x1c])
                    +        wy  * ((1.f - wx) * r1[x0c] + wx * r1[x1c]);
            ov[j] = f2bf(v);
        }
        unsigned short* dst = Xt + ((size_t)((b * 16 + y) * 64 + xo)) * 256 + cc * 64 + cj * 16;
        *reinterpret_cast<u16x8*>(dst)     = *reinterpret_cast<u16x8*>(ov);
        *reinterpret_cast<u16x8*>(dst + 8) = *reinterpret_cast<u16x8*>(ov + 8);
    }
}

// ---------------- weight transform: Wt[s][co][ci] bf16, s = ky*3+kx ----------------
__global__ void k_wt(const float* __restrict__ conv_w, unsigned short* __restrict__ Wt) {
    int e = blockIdx.x * 256 + threadIdx.x;     // 9*256*256 = 589824
    int ci = e & 255;
    int co = (e >> 8) & 255;
    int s  = e >> 16;
    Wt[(size_t)(s * 256 + co) * 256 + ci] = f2bf(conv_w[(size_t)(co * 256 + ci) * 9 + s]);
}

// ---------------- conv3x3 as MFMA implicit GEMM + fused bias/ReLU/pool → enc_bf ----------------
// grid (1024 m-tiles, 2 n-tiles), 256 threads. m-tile = (b, y0=2*(mt&7)) → 128 pixels (2 rows).
__global__ void __launch_bounds__(256) k_convmm(const unsigned short* __restrict__ Xt,
        const unsigned short* __restrict__ Wt, const float* __restrict__ conv_b,
        unsigned short* __restrict__ enc_bf) {
    __shared__ __align__(16) char smem[34048];
    unsigned short* A_s = (unsigned short*)smem;       // [128][40] bf16 (pad 40: 2-way banks, free)
    unsigned short* B_s = A_s + 128 * 40;              // [128][40]
    float* pool = (float*)smem;                        // [2][32][132] fp32 (reused after K-loop)
    const int mt = blockIdx.x;
    const int n0 = blockIdx.y * 128;
    const int b = mt >> 3;
    const int y0 = (mt & 7) * 2;
    const int tid = threadIdx.x;
    const int wave = tid >> 6, lane = tid & 63;
    const int mq = (wave & 1) * 64, nq = (wave >> 1) * 64;
    const int lm = lane & 15, lq = lane >> 4;
    f32x4 acc[4][4];
    #pragma unroll
    for (int mi = 0; mi < 4; mi++)
        #pragma unroll
        for (int ni = 0; ni < 4; ni++)
            #pragma unroll
            for (int r = 0; r < 4; r++) acc[mi][ni][r] = 0.f;

    for (int s9 = 0; s9 < 9; s9++) {
        const int ky = s9 / 3, kx = s9 % 3;
        const unsigned short* Wb = Wt + (size_t)s9 * 256 * 256;
        for (int kc = 0; kc < 256; kc += 32) {
            __syncthreads();
            #pragma unroll
            for (int it = 0; it < 2; it++) {
                int s2 = tid + it * 256;          // 0..511
                int pix = s2 >> 2, q4 = s2 & 3;
                int yy = y0 + (pix >> 6) + ky - 1;
                int xx = (pix & 63) + kx - 1;
                u16x8 va = {0, 0, 0, 0, 0, 0, 0, 0};
                if ((unsigned)yy < 16u && (unsigned)xx < 64u)
                    va = *reinterpret_cast<const u16x8*>(
                        Xt + ((size_t)((b * 16 + yy) * 64 + xx)) * 256 + kc + q4 * 8);
                *reinterpret_cast<u16x8*>(A_s + pix * 40 + q4 * 8) = va;
                u16x8 vb = *reinterpret_cast<const u16x8*>(
                    Wb + (size_t)(n0 + pix) * 256 + kc + q4 * 8);
                *reinterpret_cast<u16x8*>(B_s + pix * 40 + q4 * 8) = vb;
            }
            __syncthreads();
            short8 af[4], bfr[4];
            #pragma unroll
            for (int mi = 0; mi < 4; mi++)
                af[mi] = *reinterpret_cast<const short8*>(A_s + (mq + mi * 16 + lm) * 40 + lq * 8);
            #pragma unroll
            for (int ni = 0; ni < 4; ni++)
                bfr[ni] = *reinterpret_cast<const short8*>(B_s + (nq + ni * 16 + lm) * 40 + lq * 8);
            #pragma unroll
            for (int mi = 0; mi < 4; mi++)
                #pragma unroll
                for (int ni = 0; ni < 4; ni++)
                    acc[mi][ni] = __builtin_amdgcn_mfma_f32_16x16x32_bf16(
                        af[mi], bfr[ni], acc[mi][ni], 0, 0, 0);
        }
    }
    __syncthreads();
    // epilogue: x-pair max in-register (rows 2r,2r+1 are regs (0,1),(2,3)), stash per-y-half
    #pragma unroll
    for (int mi = 0; mi < 4; mi++) {
        int px0 = mi * 8 + lq * 2;
        #pragma unroll
        for (int ni = 0; ni < 4; ni++) {
            int nl = nq + ni * 16 + lm;
            float pa = fmaxf(acc[mi][ni][0], acc[mi][ni][1]);
            float pb = fmaxf(acc[mi][ni][2], acc[mi][ni][3]);
            pool[((wave & 1) * 32 + px0) * 132 + nl] = pa;
            pool[((wave & 1) * 32 + px0 + 1) * 132 + nl] = pb;
        }
    }
    __syncthreads();
    // combine y-halves + bias + relu + bf16 store (16 outputs/thread, n-contiguous)
    {
        int base = tid * 16;
        int px = base >> 7;
        int nb = base & 127;
        unsigned short ov[16];
        #pragma unroll
        for (int i = 0; i < 16; i++) {
            int n = nb + i;
            float v = fmaxf(pool[px * 132 + n], pool[(32 + px) * 132 + n]) + conv_b[n0 + n];
            ov[i] = f2bf(fmaxf(v, 0.f));
        }
        unsigned short* dst = enc_bf + ((size_t)b * L + (mt & 7) * 32 + px) * CENC + n0 + nb;
        *reinterpret_cast<u16x8*>(dst)     = *reinterpret_cast<u16x8*>(ov);
        *reinterpret_cast<u16x8*>(dst + 8) = *reinterpret_cast<u16x8*>(ov + 8);
    }
}

// ---------------- positional channels 256..295 (bf16) + pos2[l][40] fp32 ----------------
__global__ void k_encpos(const float* __restrict__ x_emb, const float* __restrict__ y_emb,
                         unsigned short* __restrict__ enc_bf, float* __restrict__ pos2) {
    int b = blockIdx.x, l = threadIdx.x;
    int yl = l >> 5, xl = l & 31;
    unsigned short* e = enc_bf + (size_t)(b * L + l) * CENC + 256;
    #pragma unroll
    for (int c = 0; c < 32; c++) e[c] = f2bf(x_emb[xl * 32 + c]);
    #pragma unroll
    for (int c = 0; c < 8; c++) e[32 + c] = f2bf(y_emb[yl * 8 + c]);
    if (b == 0) {
        #pragma unroll
        for (int c = 0; c < 40; c++)
            pos2[l * 40 + c] = (c < 32) ? x_emb[xl * 32 + c] : y_emb[yl * 8 + (c - 32)];
    }
}

// ---------------- enc_t[b][c][l] bf16 (c < 256) transpose for stepA phase 4 ----------------
__global__ void __launch_bounds__(256) k_enct(const unsigned short* __restrict__ enc_bf,
                                              unsigned short* __restrict__ enc_t) {
    __shared__ unsigned short s[64 * 264];   // [c 64][l 256 + pad 8] = 33KB
    const int c0 = blockIdx.x * 64;
    const int b = blockIdx.y;
    const int tid = threadIdx.x;
    // stage: thread = l, read 64 c's
    #pragma unroll
    for (int j = 0; j < 8; j++) {
        u16x8 u = *reinterpret_cast<const u16x8*>(
            enc_bf + ((size_t)b * L + tid) * CENC + c0 + j * 8);
        #pragma unroll
        for (int k = 0; k < 8; k++) s[(j * 8 + k) * 264 + tid] = u[k];
    }
    __syncthreads();
    // write: thread = (c = tid>>2, lpart = tid&3), 64 l contiguous
    {
        int c = tid >> 2, lp = tid & 3;
        const unsigned short* row = s + c * 264 + lp * 64;
        unsigned short* dst = enc_t + ((size_t)b * 256 + c0 + c) * L + lp * 64;
        #pragma unroll
        for (int i = 0; i < 8; i++)
            *reinterpret_cast<u16x8*>(dst + i * 8) =
                *reinterpret_cast<const u16x8*>(row + i * 8);
    }
}

// ---------------- E[v][h] ----------------
__global__ void __launch_bounds__(256) k_etab(const float* __restrict__ emb_dec,
                                              const float* __restrict__ word_w,
                                              const float* __restrict__ word_b,
                                              float* __restrict__ E) {
    __shared__ float er[NC];
    int row = blockIdx.x, tid = threadIdx.x;
    for (int k = tid; k < NC; k += 256) er[k] = emb_dec[(size_t)row * NC + k];
    __syncthreads();
    float a = word_b[tid];
    for (int k = 0; k < NC; k++) a += er[k] * word_w[(size_t)tid * NC + k];
    E[(size_t)row * HID + tid] = a;
}

// ---------------- transposed weight copies ----------------
__global__ void k_transW(const float* __restrict__ attn_w, const float* __restrict__ out_w,
                         unsigned short* __restrict__ wT_bf, unsigned short* __restrict__ owT_bf,
                         float* __restrict__ owT) {
    int k = blockIdx.x, tid = threadIdx.x;
    wT_bf[(size_t)k * HID + tid] = f2bf(attn_w[(size_t)tid * 552 + k]);
    if (tid < NC) {
        float v = out_w[(size_t)tid * HID + k];
        owT_bf[(size_t)k * NC + tid] = f2bf(v);
        owT[(size_t)k * NC + tid] = v;
    }
}

// ---------------- ep_t[b][l][h] = sum_c enc[b][l][c] * attn_w[h][256+c] (bf16, transposed) ----------------
__global__ void __launch_bounds__(256) k_ep(const unsigned short* __restrict__ enc_bf,
                                            const float* __restrict__ attn_w,
                                            unsigned short* __restrict__ ep_t) {
    __shared__ __align__(16) float eS[16][132];
    __shared__ __align__(16) float wS[16][36];
    const int l0 = blockIdx.x * 128;
    const int h0 = blockIdx.y * 32;
    const int b = blockIdx.z;
    const int tid = threadIdx.x;
    const int hh = tid >> 5, ll = tid & 31;
    float acc[4][4];
    #pragma unroll
    for (int s2 = 0; s2 < 4; s2++)
        #pragma unroll
        for (int r = 0; r < 4; r++) acc[s2][r] = 0.f;
    for (int kc = 0; kc < CENC; kc += 16) {
        const int kn = min(16, CENC - kc);
        __syncthreads();
        #pragma unroll
        for (int it = 0; it < 2; it++) {
            int idx = it * 256 + tid;
            int lq = idx >> 2, kq = idx & 3;
            float v0 = 0.f, v1 = 0.f, v2 = 0.f, v3 = 0.f;
            if (kq * 4 < kn) {
                ushort4 u = *reinterpret_cast<const ushort4*>(
                    enc_bf + (size_t)(b * L + l0 + lq) * CENC + kc + kq * 4);
                v0 = bf2f(u.x); v1 = bf2f(u.y); v2 = bf2f(u.z); v3 = bf2f(u.w);
            }
            eS[kq * 4 + 0][lq] = v0; eS[kq * 4 + 1][lq] = v1;
            eS[kq * 4 + 2][lq] = v2; eS[kq * 4 + 3][lq] = v3;
        }
        if (tid < 128) {
            int hq = tid >> 2, kq = tid & 3;
            float4 v = make_float4(0.f, 0.f, 0.f, 0.f);
            if (kq * 4 < kn)
                v = *reinterpret_cast<const float4*>(attn_w + (size_t)(h0 + hq) * 552 + 256 + kc + kq * 4);
            wS[kq * 4 + 0][hq] = v.x; wS[kq * 4 + 1][hq] = v.y;
            wS[kq * 4 + 2][hq] = v.z; wS[kq * 4 + 3][hq] = v.w;
        }
        __syncthreads();
        #pragma unroll
        for (int k = 0; k < 16; k++) {
            float4 e = *reinterpret_cast<const float4*>(&eS[k][ll * 4]);
            float4 w = *reinterpret_cast<const float4*>(&wS[k][hh * 4]);
            float ev[4] = {e.x, e.y, e.z, e.w};
            float wv[4] = {w.x, w.y, w.z, w.w};
            #pragma unroll
            for (int s2 = 0; s2 < 4; s2++)
                #pragma unroll
                for (int r = 0; r < 4; r++) acc[s2][r] += wv[s2] * ev[r];
        }
    }
    // transposed write: ep_t[b][l][h], 4 h-contiguous per store
    #pragma unroll
    for (int r = 0; r < 4; r++) {
        ushort4 o;
        o.x = f2bf(acc[0][r]); o.y = f2bf(acc[1][r]);
        o.z = f2bf(acc[2][r]); o.w = f2bf(acc[3][r]);
        *reinterpret_cast<ushort4*>(
            ep_t + ((size_t)(b * L) + l0 + ll * 4 + r) * HID + h0 + hh * 4) = o;
    }
}

// ---------------- per-step phase A ----------------
__global__ void __launch_bounds__(1024) k_stepA(int t,
        const float* __restrict__ hbuf, const unsigned short* __restrict__ ep_t,
        const unsigned short* __restrict__ enc_t, const unsigned short* __restrict__ wT_bf,
        const float* __restrict__ attn_b, const float* __restrict__ attn_v,
        const unsigned short* __restrict__ owT_bf, const float* __restrict__ out_b,
        const int* __restrict__ dec_tgt, const int* __restrict__ word_tgt,
        const float* __restrict__ E, const float* __restrict__ pos2,
        float* __restrict__ rin, float* __restrict__ nll) {
    const int b = blockIdx.x, tid = threadIdx.x;
    const int o = tid & 255, q = tid >> 8;
    __shared__ float hS[256], hpS[256], sS[256], vS[256];
    __shared__ float part[4][256];
    __shared__ float part2[16][40];
    __shared__ float red[16];
    if (tid < 256) {
        hS[tid] = hbuf[((size_t)(t & 1) * B + b) * HID + tid];
        vS[tid] = attn_v[tid];
    }
    __syncthreads();

    // phase 1 (t>0): prev-step logits + nll
    if (t > 0) {
        float pl = 0.f;
        if (o < NC) {
            const unsigned short* wc = owT_bf + (size_t)(q * 64) * NC + o;
            #pragma unroll 4
            for (int k = 0; k < 64; k++) pl += bf2f(wc[(size_t)k * NC]) * hS[q * 64 + k];
        }
        part[q][o] = pl;
        __syncthreads();
        float lg = -1e30f;
        if (tid < 256) {
            if (tid < NC)
                lg = out_b[tid] + part[0][tid] + part[1][tid] + part[2][tid] + part[3][tid];
            float m = wave_red_max(lg);
            if ((tid & 63) == 0) red[tid >> 6] = m;
        }
        __syncthreads();
        float M = fmaxf(fmaxf(red[0], red[1]), fmaxf(red[2], red[3]));
        if (tid < 256) {
            sS[tid] = lg;
            float e = (tid < NC) ? __expf(lg - M) : 0.f;
            float sm = wave_red_sum(e);
            if ((tid & 63) == 0) red[8 + (tid >> 6)] = sm;
        }
        __syncthreads();
        if (tid == 0) {
            float S = red[8] + red[9] + red[10] + red[11];
            int tgt = word_tgt[b * T + (t - 1)];
            if (tgt >= 0) nll[b] += M + __logf(S) - sS[tgt];
        }
        __syncthreads();
    }

    // phase 2: hp = h @ Wh^T + attn_b
    {
        float ph = 0.f;
        const unsigned short* wc = wT_bf + (size_t)(q * 64) * HID + o;
        #pragma unroll 4
        for (int k = 0; k < 64; k++) ph += bf2f(wc[(size_t)k * HID]) * hS[q * 64 + k];
        part[q][o] = ph;
    }
    __syncthreads();
    if (tid < 256)
        hpS[tid] = attn_b[tid] + part[0][tid] + part[1][tid] + part[2][tid] + part[3][tid];
    __syncthreads();

    // phase 3: scores — thread (o = l, q = h-chunk), contiguous 16B row loads
    {
        const u16x8* rowp = reinterpret_cast<const u16x8*>(
            ep_t + ((size_t)(b * L) + o) * HID + q * 64);
        float ps = 0.f;
        #pragma unroll
        for (int c8 = 0; c8 < 8; c8++) {
            u16x8 u = rowp[c8];
            int hb = q * 64 + c8 * 8;
            #pragma unroll
            for (int j = 0; j < 8; j++)
                ps += vS[hb + j] * fast_tanh(bf2f(u[j]) + hpS[hb + j]);
        }
        part[q][o] = ps;
    }
    __syncthreads();
    float sc = -1e30f;
    if (tid < 256) {
        sc = part[0][tid] + part[1][tid] + part[2][tid] + part[3][tid];
        float m = wave_red_max(sc);
        if ((tid & 63) == 0) red[tid >> 6] = m;
    }
    __syncthreads();
    float M2 = fmaxf(fmaxf(red[0], red[1]), fmaxf(red[2], red[3]));
    if (tid < 256) {
        float e2 = __expf(sc - M2);
        sS[tid] = e2;
        float sm = wave_red_sum(e2);
        if ((tid & 63) == 0) red[8 + (tid >> 6)] = sm;
    }
    __syncthreads();
    float invS = __builtin_amdgcn_rcpf(red[8] + red[9] + red[10] + red[11]);

    // phase 4: ctx channels 0..255 — thread (o = c, q = l-chunk), contiguous 16B row loads
    {
        const u16x8* rowp = reinterpret_cast<const u16x8*>(
            enc_t + ((size_t)(b * 256) + o) * L + q * 64);
        float pc = 0.f;
        #pragma unroll
        for (int c8 = 0; c8 < 8; c8++) {
            u16x8 u = rowp[c8];
            int lb = q * 64 + c8 * 8;
            #pragma unroll
            for (int j = 0; j < 8; j++) pc += sS[lb + j] * bf2f(u[j]);
        }
        part[q][o] = pc;
    }
    __syncthreads();
    if (tid < 256)
        rin[(size_t)b * 552 + 256 + tid] =
            (part[0][tid] + part[1][tid] + part[2][tid] + part[3][tid]) * invS;

    // phase 4b: positional channels via pos2 table
    {
        int c2 = tid & 63, q2 = tid >> 6;
        if (c2 < 40) {
            float pc2 = 0.f;
            #pragma unroll 4
            for (int l = 0; l < 16; l++)
                pc2 += sS[q2 * 16 + l] * pos2[(q2 * 16 + l) * 40 + c2];
            part2[q2][c2] = pc2;
        }
    }
    __syncthreads();
    if (tid < 40) {
        float s = 0.f;
        #pragma unroll
        for (int j = 0; j < 16; j++) s += part2[j][tid];
        rin[(size_t)b * 552 + 512 + tid] = s * invS;
    }

    // phase 5: word embedding gather
    if (tid < 256) {
        int tok = (t == 0) ? 0 : dec_tgt[b * T + (t - 1)];
        rin[(size_t)b * 552 + tid] = E[(size_t)tok * HID + tid];
    }
}

// ---------------- per-step phase B: batched GRU ----------------
__global__ void __launch_bounds__(256) k_stepB(const float* __restrict__ rin,
        const float* __restrict__ hbuf_r, float* __restrict__ hbuf_w,
        const float* __restrict__ wih, const float* __restrict__ bih,
        const float* __restrict__ whh, const float* __restrict__ bhh) {
    __shared__ float rS[16][552];
    __shared__ float hSS[16][256];
    __shared__ float wS[48][33];
    const int h0 = blockIdx.x * 16;
    const int b0 = blockIdx.y * 16;
    const int tid = threadIdx.x;
    const int i = tid >> 4, j = tid & 15;
    for (int r = 0; r < 16; r++)
        for (int k = tid; k < 552; k += 256) rS[r][k] = rin[(size_t)(b0 + r) * 552 + k];
    for (int r = 0; r < 16; r++) hSS[r][tid] = hbuf_r[(size_t)(b0 + r) * HID + tid];
    float aI0 = bih[h0 + j], aI1 = bih[256 + h0 + j], aI2 = bih[512 + h0 + j];
    float aH0 = bhh[h0 + j], aH1 = bhh[256 + h0 + j], aH2 = bhh[512 + h0 + j];
    for (int kc = 0; kc < 552; kc += 32) {
        int kn = min(32, 552 - kc);
        __syncthreads();
        for (int idx = tid; idx < 48 * 32; idx += 256) {
            int r = idx >> 5, k = idx & 31;
            wS[r][k] = (k < kn) ? wih[(size_t)((r >> 4) * 256 + h0 + (r & 15)) * 552 + kc + k] : 0.f;
        }
        __syncthreads();
        for (int k = 0; k < kn; k++) {
            float rv = rS[i][kc + k];
            aI0 += wS[j][k] * rv; aI1 += wS[16 + j][k] * rv; aI2 += wS[32 + j][k] * rv;
        }
    }
    for (int kc = 0; kc < 256; kc += 32) {
        __syncthreads();
        for (int idx = tid; idx < 48 * 32; idx += 256) {
            int r = idx >> 5, k = idx & 31;
            wS[r][k] = whh[(size_t)((r >> 4) * 256 + h0 + (r & 15)) * HID + kc + k];
        }
        __syncthreads();
        #pragma unroll 8
        for (int k = 0; k < 32; k++) {
            float hv = hSS[i][kc + k];
            aH0 += wS[j][k] * hv; aH1 += wS[16 + j][k] * hv; aH2 += wS[32 + j][k] * hv;
        }
    }
    float r_ = fast_sigm(aI0 + aH0);
    float z_ = fast_sigm(aI1 + aH1);
    float n_ = fast_tanh(aI2 + r_ * aH2);
    float hold = hSS[i][h0 + j];
    hbuf_w[(size_t)(b0 + i) * HID + h0 + j] = (1.f - z_) * n_ + z_ * hold;
}

// ---------------- final step-31 NLL ----------------
__global__ void __launch_bounds__(256) k_finalnll(const float* __restrict__ hbuf,
        const float* __restrict__ owT, const float* __restrict__ out_b,
        const int* __restrict__ word_tgt, float* __restrict__ nll) {
    const int b = blockIdx.x, tid = threadIdx.x;
    __shared__ float hS[256], sS[256];
    __shared__ float red[8];
    hS[tid] = hbuf[(size_t)b * HID + tid];
    __syncthreads();
    float lg = -1e30f;
    if (tid < NC) {
        float a = out_b[tid];
        #pragma unroll 4
        for (int k = 0; k < HID; k++) a += owT[(size_t)k * NC + tid] * hS[k];
        lg = a;
    }
    float m = wave_red_max(lg);
    if ((tid & 63) == 0) red[tid >> 6] = m;
    __syncthreads();
    float M = fmaxf(fmaxf(red[0], red[1]), fmaxf(red[2], red[3]));
    __syncthreads();
    float e = (tid < NC) ? __expf(lg - M) : 0.f;
    float sm = wave_red_sum(e);
    if ((tid & 63) == 0) red[tid >> 6] = sm;
    sS[tid] = lg;
    __syncthreads();
    float S = red[0] + red[1] + red[2] + red[3];
    if (tid == 0) {
        int tgt = word_tgt[b * T + (T - 1)];
        if (tgt >= 0) nll[b] += M + __logf(S) - sS[tgt];
    }
}

// ---------------- loss ----------------
__global__ void k_reduce(const float* __restrict__ nll, float* __restrict__ out) {
    __shared__ float red[2];
    float v = nll[threadIdx.x];
    v = wave_red_sum(v);
    if ((threadIdx.x & 63) == 0) red[threadIdx.x >> 6] = v;
    __syncthreads();
    if (threadIdx.x == 0) out[0] = 0.2f * (red[0] + red[1]) * (1.f / 128.f);
}

extern "C" void kernel_launch(void* const* d_in, const int* in_sizes, int n_in,
                              void* d_out, int out_size, void* d_ws, size_t ws_size,
                              hipStream_t stream) {
    const float* x        = (const float*)d_in[0];
    const int*   dec_tgt  = (const int*)d_in[1];
    const int*   word_tgt = (const int*)d_in[2];
    const float* conv_w   = (const float*)d_in[3];
    const float* conv_b   = (const float*)d_in[4];
    const float* emb_dec  = (const float*)d_in[5];
    const float* word_w   = (const float*)d_in[6];
    const float* word_b   = (const float*)d_in[7];
    const float* attn_w   = (const float*)d_in[8];
    const float* attn_b   = (const float*)d_in[9];
    const float* attn_v   = (const float*)d_in[10];
    const float* gru_wih  = (const float*)d_in[11];
    const float* gru_bih  = (const float*)d_in[12];
    const float* gru_whh  = (const float*)d_in[13];
    const float* gru_bhh  = (const float*)d_in[14];
    const float* out_w    = (const float*)d_in[15];
    const float* out_b    = (const float*)d_in[16];
    const float* x_emb    = (const float*)d_in[17];
    const float* y_emb    = (const float*)d_in[18];

    char* ws = (char*)d_ws;
    size_t off = 0;
    auto alloc = [&](size_t bytes) -> void* {
        void* p = ws + off;
        off = (off + bytes + 255) & ~(size_t)255;
        return p;
    };
    unsigned short* Xt     = (unsigned short*)alloc((size_t)B * 16 * 64 * 256 * 2);  // 67MB
    unsigned short* enc_bf = (unsigned short*)alloc((size_t)B * L * CENC * 2);        // 19.4MB
    unsigned short* Wt     = (unsigned short*)alloc((size_t)9 * 256 * 256 * 2);       // 1.2MB
    float* E      = (float*)alloc((size_t)NC * HID * 4);
    float* owT    = (float*)alloc((size_t)HID * NC * 4);
    unsigned short* wT_bf  = (unsigned short*)alloc((size_t)HID * HID * 2);
    unsigned short* owT_bf = (unsigned short*)alloc((size_t)HID * NC * 2);
    float* pos2   = (float*)alloc((size_t)L * 40 * 4);
    float* rin    = (float*)alloc((size_t)B * 552 * 4);
    float* hbuf   = (float*)alloc((size_t)2 * B * HID * 4);
    float* nll    = (float*)alloc((size_t)B * 4);
    // ep_t / enc_t alias Xt (dead after k_convmm): 16.8MB + 16.8MB < 67MB
    unsigned short* ep_t  = Xt;
    unsigned short* enc_t = Xt + (size_t)B * L * HID;
    float* out    = (float*)d_out;

    hipLaunchKernelGGL(k_init, dim3(128), dim3(256), 0, stream, hbuf, nll);
    hipLaunchKernelGGL(k_upsxt, dim3(16, 128), dim3(256), 0, stream, x, Xt);
    hipLaunchKernelGGL(k_wt, dim3(2304), dim3(256), 0, stream, conv_w, Wt);
    hipLaunchKernelGGL(k_encpos, dim3(128), dim3(256), 0, stream, x_emb, y_emb, enc_bf, pos2);
    hipLaunchKernelGGL(k_convmm, dim3(1024, 2), dim3(256), 0, stream, Xt, Wt, conv_b, enc_bf);
    hipLaunchKernelGGL(k_etab, dim3(163), dim3(256), 0, stream, emb_dec, word_w, word_b, E);
    hipLaunchKernelGGL(k_transW, dim3(256), dim3(256), 0, stream, attn_w, out_w, wT_bf, owT_bf, owT);
    hipLaunchKernelGGL(k_ep, dim3(2, 8, 128), dim3(256), 0, stream, enc_bf, attn_w, ep_t);
    hipLaunchKernelGGL(k_enct, dim3(4, 128), dim3(256), 0, stream, enc_bf, enc_t);
    for (int t = 0; t < T; t++) {
        hipLaunchKernelGGL(k_stepA, dim3(128), dim3(1024), 0, stream, t,
                           hbuf, ep_t, enc_t, wT_bf, attn_b, attn_v, owT_bf, out_b,
                           dec_tgt, word_tgt, E, pos2, rin, nll);
        const float* hr = hbuf + (size_t)(t & 1) * B * HID;
        float* hw = hbuf + (size_t)((t + 1) & 1) * B * HID;
        hipLaunchKernelGGL(k_stepB, dim3(16, 8), dim3(256), 0, stream,
                           rin, hr, hw, gru_wih, gru_bih, gru_whh, gru_bhh);
    }
    hipLaunchKernelGGL(k_finalnll, dim3(128), dim3(256), 0, stream, hbuf, owT, out_b, word_tgt, nll);
    hipLaunchKernelGGL(k_reduce, dim3(1), dim3(128), 0, stream, nll, out);
}

// Round 4
// 1912.763 us; speedup vs baseline: 4.2108x; 1.9953x over previous
//
#include <hip/hip_runtime.h>
#include <hip/hip_bf16.h>
#include <math.h>

#define B    128
#define CIN  256
#define HIN  8
#define WIN_ 32
#define RH   16
#define RW   64
#define HID  256
#define NC   163
#define T    32
#define L    256
#define CENC 296
#define RINW 832   // [0..255 emb][256..551 ctx][552..575 zero pad][576..831 h]

typedef __attribute__((ext_vector_type(8))) short short8;
typedef __attribute__((ext_vector_type(8))) unsigned short u16x8;
typedef __attribute__((ext_vector_type(4))) float f32x4;

__device__ __forceinline__ float bf2f(unsigned short u) {
    unsigned int x = ((unsigned int)u) << 16;
    return __uint_as_float(x);
}
__device__ __forceinline__ unsigned short f2bf(float f) {
    unsigned int x = __float_as_uint(f);
    unsigned int r = (x + 0x7FFFu + ((x >> 16) & 1u)) >> 16;
    return (unsigned short)r;
}
__device__ __forceinline__ float fast_tanh(float x) {
    float e = __expf(2.f * x);
    return 1.f - 2.f * __builtin_amdgcn_rcpf(e + 1.f);
}
__device__ __forceinline__ float fast_sigm(float x) {
    return __builtin_amdgcn_rcpf(1.f + __expf(-x));
}
__device__ __forceinline__ float wave_red_max(float v) {
    #pragma unroll
    for (int o = 32; o > 0; o >>= 1) v = fmaxf(v, __shfl_down(v, o, 64));
    return v;
}
__device__ __forceinline__ float wave_red_sum(float v) {
    #pragma unroll
    for (int o = 32; o > 0; o >>= 1) v += __shfl_down(v, o, 64);
    return v;
}

// ---------------- init: zero h0, nll, rin pad cols ----------------
__global__ void k_init(float* __restrict__ hbuf, float* __restrict__ nll,
                       unsigned short* __restrict__ rin) {
    int b = blockIdx.x, tid = threadIdx.x;
    hbuf[(size_t)b * HID + tid] = 0.f;
    if (tid < 24) rin[(size_t)b * RINW + 552 + tid] = 0;   // zero K-pad
    if (b == 0 && tid < B) nll[tid] = 0.f;
}

// ---------------- bilinear upsample fused with transpose → Xt[b][y][x][ci] bf16 ----------------
__global__ void __launch_bounds__(256) k_upsxt(const float* __restrict__ x,
                                               unsigned short* __restrict__ Xt) {
    __shared__ __align__(16) float sf[64 * 2 * 32];
    const int y = blockIdx.x;
    const int b = blockIdx.y;
    const int tid = threadIdx.x;
    float sy = 0.5f * y - 0.25f;
    int yq0 = (y - 1) >> 1;
    float wy = sy - (float)yq0;
    int y0c = min(max(yq0, 0), HIN - 1);
    int y1c = min(max(yq0 + 1, 0), HIN - 1);
    const int xo = tid & 63;
    const int cj = tid >> 6;
    float sx = 0.5f * xo - 0.25f;
    int xq0 = (xo - 1) >> 1;
    float wx = sx - (float)xq0;
    int x0c = min(max(xq0, 0), WIN_ - 1);
    int x1c = min(max(xq0 + 1, 0), WIN_ - 1);
    for (int cc = 0; cc < 4; cc++) {
        __syncthreads();
        #pragma unroll
        for (int i = 0; i < 4; i++) {
            int idx = tid * 4 + i;
            int c = idx >> 4;
            int rowh = (idx >> 3) & 1;
            int part = idx & 7;
            int ysrc = rowh ? y1c : y0c;
            float4 v = *reinterpret_cast<const float4*>(
                x + ((size_t)(b * CIN + cc * 64 + c) * HIN + ysrc) * WIN_ + part * 4);
            *reinterpret_cast<float4*>(sf + ((c * 2 + rowh) * 32 + part * 4)) = v;
        }
        __syncthreads();
        unsigned short ov[16];
        #pragma unroll
        for (int j = 0; j < 16; j++) {
            int c = cj * 16 + j;
            const float* r0 = sf + (c * 2 + 0) * 32;
            const float* r1 = sf + (c * 2 + 1) * 32;
            float v = (1.f - wy) * ((1.f - wx) * r0[x0c] + wx * r0[x1c])
                    +        wy  * ((1.f - wx) * r1[x0c] + wx * r1[x1c]);
            ov[j] = f2bf(v);
        }
        unsigned short* dst = Xt + ((size_t)((b * 16 + y) * 64 + xo)) * 256 + cc * 64 + cj * 16;
        *reinterpret_cast<u16x8*>(dst)     = *reinterpret_cast<u16x8*>(ov);
        *reinterpret_cast<u16x8*>(dst + 8) = *reinterpret_cast<u16x8*>(ov + 8);
    }
}

// ---------------- weight transform: Wt[s][co][ci] bf16 ----------------
__global__ void k_wt(const float* __restrict__ conv_w, unsigned short* __restrict__ Wt) {
    int e = blockIdx.x * 256 + threadIdx.x;
    int ci = e & 255;
    int co = (e >> 8) & 255;
    int s  = e >> 16;
    Wt[(size_t)(s * 256 + co) * 256 + ci] = f2bf(conv_w[(size_t)(co * 256 + ci) * 9 + s]);
}

// ---------------- conv3x3 MFMA implicit GEMM + fused bias/ReLU/pool → enc_bf ----------------
__global__ void __launch_bounds__(256) k_convmm(const unsigned short* __restrict__ Xt,
        const unsigned short* __restrict__ Wt, const float* __restrict__ conv_b,
        unsigned short* __restrict__ enc_bf) {
    __shared__ __align__(16) char smem[34048];
    unsigned short* A_s = (unsigned short*)smem;
    unsigned short* B_s = A_s + 128 * 40;
    float* pool = (float*)smem;
    const int mt = blockIdx.x;
    const int n0 = blockIdx.y * 128;
    const int b = mt >> 3;
    const int y0 = (mt & 7) * 2;
    const int tid = threadIdx.x;
    const int wave = tid >> 6, lane = tid & 63;
    const int mq = (wave & 1) * 64, nq = (wave >> 1) * 64;
    const int lm = lane & 15, lq = lane >> 4;
    f32x4 acc[4][4];
    #pragma unroll
    for (int mi = 0; mi < 4; mi++)
        #pragma unroll
        for (int ni = 0; ni < 4; ni++)
            #pragma unroll
            for (int r = 0; r < 4; r++) acc[mi][ni][r] = 0.f;

    for (int s9 = 0; s9 < 9; s9++) {
        const int ky = s9 / 3, kx = s9 % 3;
        const unsigned short* Wb = Wt + (size_t)s9 * 256 * 256;
        for (int kc = 0; kc < 256; kc += 32) {
            __syncthreads();
            #pragma unroll
            for (int it = 0; it < 2; it++) {
                int s2 = tid + it * 256;
                int pix = s2 >> 2, q4 = s2 & 3;
                int yy = y0 + (pix >> 6) + ky - 1;
                int xx = (pix & 63) + kx - 1;
                u16x8 va = {0, 0, 0, 0, 0, 0, 0, 0};
                if ((unsigned)yy < 16u && (unsigned)xx < 64u)
                    va = *reinterpret_cast<const u16x8*>(
                        Xt + ((size_t)((b * 16 + yy) * 64 + xx)) * 256 + kc + q4 * 8);
                *reinterpret_cast<u16x8*>(A_s + pix * 40 + q4 * 8) = va;
                u16x8 vb = *reinterpret_cast<const u16x8*>(
                    Wb + (size_t)(n0 + pix) * 256 + kc + q4 * 8);
                *reinterpret_cast<u16x8*>(B_s + pix * 40 + q4 * 8) = vb;
            }
            __syncthreads();
            short8 af[4], bfr[4];
            #pragma unroll
            for (int mi = 0; mi < 4; mi++)
                af[mi] = *reinterpret_cast<const short8*>(A_s + (mq + mi * 16 + lm) * 40 + lq * 8);
            #pragma unroll
            for (int ni = 0; ni < 4; ni++)
                bfr[ni] = *reinterpret_cast<const short8*>(B_s + (nq + ni * 16 + lm) * 40 + lq * 8);
            #pragma unroll
            for (int mi = 0; mi < 4; mi++)
                #pragma unroll
                for (int ni = 0; ni < 4; ni++)
                    acc[mi][ni] = __builtin_amdgcn_mfma_f32_16x16x32_bf16(
                        af[mi], bfr[ni], acc[mi][ni], 0, 0, 0);
        }
    }
    __syncthreads();
    #pragma unroll
    for (int mi = 0; mi < 4; mi++) {
        int px0 = mi * 8 + lq * 2;
        #pragma unroll
        for (int ni = 0; ni < 4; ni++) {
            int nl = nq + ni * 16 + lm;
            float pa = fmaxf(acc[mi][ni][0], acc[mi][ni][1]);
            float pb = fmaxf(acc[mi][ni][2], acc[mi][ni][3]);
            pool[((wave & 1) * 32 + px0) * 132 + nl] = pa;
            pool[((wave & 1) * 32 + px0 + 1) * 132 + nl] = pb;
        }
    }
    __syncthreads();
    {
        int base = tid * 16;
        int px = base >> 7;
        int nb = base & 127;
        unsigned short ov[16];
        #pragma unroll
        for (int i = 0; i < 16; i++) {
            int n = nb + i;
            float v = fmaxf(pool[px * 132 + n], pool[(32 + px) * 132 + n]) + conv_b[n0 + n];
            ov[i] = f2bf(fmaxf(v, 0.f));
        }
        unsigned short* dst = enc_bf + ((size_t)b * L + (mt & 7) * 32 + px) * CENC + n0 + nb;
        *reinterpret_cast<u16x8*>(dst)     = *reinterpret_cast<u16x8*>(ov);
        *reinterpret_cast<u16x8*>(dst + 8) = *reinterpret_cast<u16x8*>(ov + 8);
    }
}

// ---------------- positional channels + pos2 table ----------------
__global__ void k_encpos(const float* __restrict__ x_emb, const float* __restrict__ y_emb,
                         unsigned short* __restrict__ enc_bf, float* __restrict__ pos2) {
    int b = blockIdx.x, l = threadIdx.x;
    int yl = l >> 5, xl = l & 31;
    unsigned short* e = enc_bf + (size_t)(b * L + l) * CENC + 256;
    #pragma unroll
    for (int c = 0; c < 32; c++) e[c] = f2bf(x_emb[xl * 32 + c]);
    #pragma unroll
    for (int c = 0; c < 8; c++) e[32 + c] = f2bf(y_emb[yl * 8 + c]);
    if (b == 0) {
        #pragma unroll
        for (int c = 0; c < 40; c++)
            pos2[l * 40 + c] = (c < 32) ? x_emb[xl * 32 + c] : y_emb[yl * 8 + (c - 32)];
    }
}

// ---------------- enc_t[b][c][l] bf16 ----------------
__global__ void __launch_bounds__(256) k_enct(const unsigned short* __restrict__ enc_bf,
                                              unsigned short* __restrict__ enc_t) {
    __shared__ unsigned short s[64 * 264];
    const int c0 = blockIdx.x * 64;
    const int b = blockIdx.y;
    const int tid = threadIdx.x;
    #pragma unroll
    for (int j = 0; j < 8; j++) {
        u16x8 u = *reinterpret_cast<const u16x8*>(
            enc_bf + ((size_t)b * L + tid) * CENC + c0 + j * 8);
        #pragma unroll
        for (int k = 0; k < 8; k++) s[(j * 8 + k) * 264 + tid] = u[k];
    }
    __syncthreads();
    {
        int c = tid >> 2, lp = tid & 3;
        const unsigned short* row = s + c * 264 + lp * 64;
        unsigned short* dst = enc_t + ((size_t)b * 256 + c0 + c) * L + lp * 64;
        #pragma unroll
        for (int i = 0; i < 8; i++)
            *reinterpret_cast<u16x8*>(dst + i * 8) =
                *reinterpret_cast<const u16x8*>(row + i * 8);
    }
}

// ---------------- E_bf[v][h] bf16 ----------------
__global__ void __launch_bounds__(256) k_etab(const float* __restrict__ emb_dec,
                                              const float* __restrict__ word_w,
                                              const float* __restrict__ word_b,
                                              unsigned short* __restrict__ E_bf) {
    __shared__ float er[NC];
    int row = blockIdx.x, tid = threadIdx.x;
    for (int k = tid; k < NC; k += 256) er[k] = emb_dec[(size_t)row * NC + k];
    __syncthreads();
    float a = word_b[tid];
    for (int k = 0; k < NC; k++) a += er[k] * word_w[(size_t)tid * NC + k];
    E_bf[(size_t)row * HID + tid] = f2bf(a);
}

// ---------------- row-major bf16 weight casts: wA_bf[256][256], ow_bf[163][256] ----------------
__global__ void k_prep(const float* __restrict__ attn_w, const float* __restrict__ out_w,
                       unsigned short* __restrict__ wA_bf, unsigned short* __restrict__ ow_bf) {
    int o = blockIdx.x, k = threadIdx.x;
    wA_bf[(size_t)o * 256 + k] = f2bf(attn_w[(size_t)o * 552 + k]);
    if (o < NC) ow_bf[(size_t)o * 256 + k] = f2bf(out_w[(size_t)o * 256 + k]);
}

// ---------------- combined GRU weights: Wg1[768][576] (wih,K-pad0), Wg2[768][256] (whh) ----------------
__global__ void __launch_bounds__(576) k_wg(const float* __restrict__ wih,
                                            const float* __restrict__ whh,
                                            unsigned short* __restrict__ Wg1,
                                            unsigned short* __restrict__ Wg2) {
    int g = blockIdx.x, k = threadIdx.x;
    Wg1[(size_t)g * 576 + k] = (k < 552) ? f2bf(wih[(size_t)g * 552 + k]) : 0;
    if (k < 256) Wg2[(size_t)g * 256 + k] = f2bf(whh[(size_t)g * 256 + k]);
}

// ---------------- ep_t[b][l][h] bf16 ----------------
__global__ void __launch_bounds__(256) k_ep(const unsigned short* __restrict__ enc_bf,
                                            const float* __restrict__ attn_w,
                                            unsigned short* __restrict__ ep_t) {
    __shared__ __align__(16) float eS[16][132];
    __shared__ __align__(16) float wS[16][36];
    const int l0 = blockIdx.x * 128;
    const int h0 = blockIdx.y * 32;
    const int b = blockIdx.z;
    const int tid = threadIdx.x;
    const int hh = tid >> 5, ll = tid & 31;
    float acc[4][4];
    #pragma unroll
    for (int s2 = 0; s2 < 4; s2++)
        #pragma unroll
        for (int r = 0; r < 4; r++) acc[s2][r] = 0.f;
    for (int kc = 0; kc < CENC; kc += 16) {
        const int kn = min(16, CENC - kc);
        __syncthreads();
        #pragma unroll
        for (int it = 0; it < 2; it++) {
            int idx = it * 256 + tid;
            int lq = idx >> 2, kq = idx & 3;
            float v0 = 0.f, v1 = 0.f, v2 = 0.f, v3 = 0.f;
            if (kq * 4 < kn) {
                ushort4 u = *reinterpret_cast<const ushort4*>(
                    enc_bf + (size_t)(b * L + l0 + lq) * CENC + kc + kq * 4);
                v0 = bf2f(u.x); v1 = bf2f(u.y); v2 = bf2f(u.z); v3 = bf2f(u.w);
            }
            eS[kq * 4 + 0][lq] = v0; eS[kq * 4 + 1][lq] = v1;
            eS[kq * 4 + 2][lq] = v2; eS[kq * 4 + 3][lq] = v3;
        }
        if (tid < 128) {
            int hq = tid >> 2, kq = tid & 3;
            float4 v = make_float4(0.f, 0.f, 0.f, 0.f);
            if (kq * 4 < kn)
                v = *reinterpret_cast<const float4*>(attn_w + (size_t)(h0 + hq) * 552 + 256 + kc + kq * 4);
            wS[kq * 4 + 0][hq] = v.x; wS[kq * 4 + 1][hq] = v.y;
            wS[kq * 4 + 2][hq] = v.z; wS[kq * 4 + 3][hq] = v.w;
        }
        __syncthreads();
        #pragma unroll
        for (int k = 0; k < 16; k++) {
            float4 e = *reinterpret_cast<const float4*>(&eS[k][ll * 4]);
            float4 w = *reinterpret_cast<const float4*>(&wS[k][hh * 4]);
            float ev[4] = {e.x, e.y, e.z, e.w};
            float wv[4] = {w.x, w.y, w.z, w.w};
            #pragma unroll
            for (int s2 = 0; s2 < 4; s2++)
                #pragma unroll
                for (int r = 0; r < 4; r++) acc[s2][r] += wv[s2] * ev[r];
        }
    }
    #pragma unroll
    for (int r = 0; r < 4; r++) {
        ushort4 o;
        o.x = f2bf(acc[0][r]); o.y = f2bf(acc[1][r]);
        o.z = f2bf(acc[2][r]); o.w = f2bf(acc[3][r]);
        *reinterpret_cast<ushort4*>(
            ep_t + ((size_t)(b * L) + l0 + ll * 4 + r) * HID + h0 + hh * 4) = o;
    }
}

// ---------------- per-step phase A: GRU pointwise + nll + attention → rin ----------------
// thread (o = tid>>2, q = tid&3): consecutive tids read consecutive 128B spans.
__global__ void __launch_bounds__(1024) k_stepA(int t,
        float* __restrict__ hbuf, const float* __restrict__ gbuf,
        const float* __restrict__ bih, const float* __restrict__ bhh,
        const unsigned short* __restrict__ ep_t, const unsigned short* __restrict__ enc_t,
        const unsigned short* __restrict__ wA_bf, const float* __restrict__ attn_b,
        const float* __restrict__ attn_v, const unsigned short* __restrict__ ow_bf,
        const float* __restrict__ out_b, const int* __restrict__ dec_tgt,
        const int* __restrict__ word_tgt, const unsigned short* __restrict__ E_bf,
        const float* __restrict__ pos2, unsigned short* __restrict__ rin,
        float* __restrict__ nll) {
    const int b = blockIdx.x, tid = threadIdx.x;
    const int o = tid >> 2, q = tid & 3;
    __shared__ float hq[4][68], vq[4][68], hpq[4][68], sq[4][68];
    __shared__ float pb[1024];
    __shared__ float lgS[256];
    __shared__ float part2[40][17];
    __shared__ float red[16];

    // s0: GRU pointwise (h_t from gates of step t-1), stash h
    if (tid < 256) {
        float h;
        if (t == 0) {
            h = 0.f;
        } else {
            float hold = hbuf[(size_t)b * HID + tid];
            const float* gi = gbuf + (size_t)b * 768;
            const float* gh = gbuf + (size_t)128 * 768 + (size_t)b * 768;
            float r_ = fast_sigm(gi[tid] + bih[tid] + gh[tid] + bhh[tid]);
            float z_ = fast_sigm(gi[256 + tid] + bih[256 + tid] + gh[256 + tid] + bhh[256 + tid]);
            float n_ = fast_tanh(gi[512 + tid] + bih[512 + tid] + r_ * (gh[512 + tid] + bhh[512 + tid]));
            h = (1.f - z_) * n_ + z_ * hold;
            hbuf[(size_t)b * HID + tid] = h;
        }
        rin[(size_t)b * RINW + 576 + tid] = f2bf(h);
        hq[tid >> 6][tid & 63] = h;
        vq[tid >> 6][tid & 63] = attn_v[tid];
    }
    __syncthreads();

    // s1 (t>0): logits(h_t) + nll vs word_targets[t-1]
    if (t > 0) {
        float pl = 0.f;
        if (o < NC) {
            const u16x8* wp = reinterpret_cast<const u16x8*>(ow_bf + (size_t)o * 256 + q * 64);
            #pragma unroll
            for (int c8 = 0; c8 < 8; c8++) {
                u16x8 u = wp[c8];
                #pragma unroll
                for (int j = 0; j < 8; j++) pl += bf2f(u[j]) * hq[q][c8 * 8 + j];
            }
        }
        pb[tid] = pl;
        __syncthreads();
        float lg = -1e30f;
        if (tid < 256) {
            if (tid < NC) {
                float4 p4 = *reinterpret_cast<const float4*>(&pb[tid * 4]);
                lg = out_b[tid] + p4.x + p4.y + p4.z + p4.w;
            }
            lgS[tid] = lg;
            float m = wave_red_max(lg);
            if ((tid & 63) == 0) red[tid >> 6] = m;
        }
        __syncthreads();
        float M = fmaxf(fmaxf(red[0], red[1]), fmaxf(red[2], red[3]));
        if (tid < 256) {
            float e = (tid < NC) ? __expf(lg - M) : 0.f;
            float sm = wave_red_sum(e);
            if ((tid & 63) == 0) red[8 + (tid >> 6)] = sm;
        }
        __syncthreads();
        if (tid == 0) {
            float S = red[8] + red[9] + red[10] + red[11];
            int tgt = word_tgt[b * T + (t - 1)];
            if (tgt >= 0) nll[b] += M + __logf(S) - lgS[tgt];
        }
    }
    __syncthreads();

    // s2: hp = h @ Wh^T + attn_b
    {
        float ph = 0.f;
        const u16x8* wp = reinterpret_cast<const u16x8*>(wA_bf + (size_t)o * 256 + q * 64);
        #pragma unroll
        for (int c8 = 0; c8 < 8; c8++) {
            u16x8 u = wp[c8];
            #pragma unroll
            for (int j = 0; j < 8; j++) ph += bf2f(u[j]) * hq[q][c8 * 8 + j];
        }
        pb[tid] = ph;
    }
    __syncthreads();
    if (tid < 256) {
        float4 p4 = *reinterpret_cast<const float4*>(&pb[tid * 4]);
        hpq[tid >> 6][tid & 63] = attn_b[tid] + p4.x + p4.y + p4.z + p4.w;
    }
    __syncthreads();

    // s3: scores (l = o)
    {
        float ps = 0.f;
        const u16x8* ep = reinterpret_cast<const u16x8*>(
            ep_t + ((size_t)(b * L) + o) * HID + q * 64);
        #pragma unroll
        for (int c8 = 0; c8 < 8; c8++) {
            u16x8 u = ep[c8];
            #pragma unroll
            for (int j = 0; j < 8; j++) {
                int ii = c8 * 8 + j;
                ps += vq[q][ii] * fast_tanh(bf2f(u[j]) + hpq[q][ii]);
            }
        }
        pb[tid] = ps;
    }
    __syncthreads();
    float sc = 0.f;
    if (tid < 256) {
        float4 p4 = *reinterpret_cast<const float4*>(&pb[tid * 4]);
        sc = p4.x + p4.y + p4.z + p4.w;
        float m = wave_red_max(sc);
        if ((tid & 63) == 0) red[tid >> 6] = m;
    }
    __syncthreads();
    float M2 = fmaxf(fmaxf(red[0], red[1]), fmaxf(red[2], red[3]));
    if (tid < 256) {
        float e2 = __expf(sc - M2);
        sq[tid >> 6][tid & 63] = e2;
        float sm = wave_red_sum(e2);
        if ((tid & 63) == 0) red[8 + (tid >> 6)] = sm;
    }
    __syncthreads();
    float invS = __builtin_amdgcn_rcpf(red[8] + red[9] + red[10] + red[11]);

    // s4: ctx channels 0..255 (c = o, l-chunk = q) + s4b positional partials
    {
        float pc = 0.f;
        const u16x8* eb = reinterpret_cast<const u16x8*>(
            enc_t + ((size_t)(b * 256) + o) * L + q * 64);
        #pragma unroll
        for (int c8 = 0; c8 < 8; c8++) {
            u16x8 u = eb[c8];
            #pragma unroll
            for (int j = 0; j < 8; j++) pc += sq[q][c8 * 8 + j] * bf2f(u[j]);
        }
        pb[tid] = pc;
    }
    {
        int c2 = tid >> 4, l16 = tid & 15;
        if (c2 < 40) {
            float p = 0.f;
            #pragma unroll 4
            for (int i = 0; i < 16; i++) {
                int l = l16 * 16 + i;
                p += sq[l >> 6][l & 63] * pos2[l * 40 + c2];
            }
            part2[c2][l16] = p;
        }
    }
    __syncthreads();
    if (tid < 256) {
        float4 p4 = *reinterpret_cast<const float4*>(&pb[tid * 4]);
        rin[(size_t)b * RINW + 256 + tid] = f2bf((p4.x + p4.y + p4.z + p4.w) * invS);
        int tok = (t == 0) ? 0 : dec_tgt[b * T + (t - 1)];
        rin[(size_t)b * RINW + tid] = E_bf[(size_t)tok * HID + tid];
    }
    if (tid < 40) {
        float s = 0.f;
        #pragma unroll
        for (int j = 0; j < 16; j++) s += part2[tid][j];
        rin[(size_t)b * RINW + 512 + tid] = f2bf(s * invS);
    }
}

// ---------------- per-step phase B: MFMA GEMM → gi (blocks 0..5) / gh (blocks 6..11) ----------------
__global__ void __launch_bounds__(256) k_stepB(const unsigned short* __restrict__ rin,
        const unsigned short* __restrict__ Wg1, const unsigned short* __restrict__ Wg2,
        float* __restrict__ gbuf) {
    __shared__ __align__(16) unsigned short A_s[128 * 40];
    __shared__ __align__(16) unsigned short B_s[128 * 40];
    const int nt = blockIdx.x;
    const int half = (nt >= 6) ? 1 : 0;
    const int n0 = (nt - half * 6) * 128;
    const int K = half ? 256 : 576;
    const int Aoff = half ? 576 : 0;
    const unsigned short* W = half ? Wg2 : Wg1;
    const int Wst = half ? 256 : 576;
    const int tid = threadIdx.x;
    const int wave = tid >> 6, lane = tid & 63;
    const int mq = (wave & 1) * 64, nq = (wave >> 1) * 64;
    const int lm = lane & 15, lq = lane >> 4;
    f32x4 acc[4][4];
    #pragma unroll
    for (int mi = 0; mi < 4; mi++)
        #pragma unroll
        for (int ni = 0; ni < 4; ni++)
            #pragma unroll
            for (int r = 0; r < 4; r++) acc[mi][ni][r] = 0.f;
    for (int kc = 0; kc < K; kc += 32) {
        __syncthreads();
        #pragma unroll
        for (int it = 0; it < 2; it++) {
            int s2 = tid + it * 256;
            int row = s2 >> 2, q4 = s2 & 3;
            *reinterpret_cast<u16x8*>(A_s + row * 40 + q4 * 8) =
                *reinterpret_cast<const u16x8*>(rin + (size_t)row * RINW + Aoff + kc + q4 * 8);
            *reinterpret_cast<u16x8*>(B_s + row * 40 + q4 * 8) =
                *reinterpret_cast<const u16x8*>(W + (size_t)(n0 + row) * Wst + kc + q4 * 8);
        }
        __syncthreads();
        short8 af[4], bfr[4];
        #pragma unroll
        for (int mi = 0; mi < 4; mi++)
            af[mi] = *reinterpret_cast<const short8*>(A_s + (mq + mi * 16 + lm) * 40 + lq * 8);
        #pragma unroll
        for (int ni = 0; ni < 4; ni++)
            bfr[ni] = *reinterpret_cast<const short8*>(B_s + (nq + ni * 16 + lm) * 40 + lq * 8);
        #pragma unroll
        for (int mi = 0; mi < 4; mi++)
            #pragma unroll
            for (int ni = 0; ni < 4; ni++)
                acc[mi][ni] = __builtin_amdgcn_mfma_f32_16x16x32_bf16(
                    af[mi], bfr[ni], acc[mi][ni], 0, 0, 0);
    }
    float* outp = gbuf + (size_t)half * 128 * 768;
    #pragma unroll
    for (int mi = 0; mi < 4; mi++)
        #pragma unroll
        for (int ni = 0; ni < 4; ni++) {
            int g = n0 + nq + ni * 16 + lm;
            int b0 = mq + mi * 16 + lq * 4;
            #pragma unroll
            for (int r = 0; r < 4; r++)
                outp[(size_t)(b0 + r) * 768 + g] = acc[mi][ni][r];
        }
}

// ---------------- final: pointwise h_32 + step-31 NLL ----------------
__global__ void __launch_bounds__(256) k_finalnll(const float* __restrict__ hbuf,
        const float* __restrict__ gbuf, const float* __restrict__ bih,
        const float* __restrict__ bhh, const unsigned short* __restrict__ ow_bf,
        const float* __restrict__ out_b, const int* __restrict__ word_tgt,
        float* __restrict__ nll) {
    const int b = blockIdx.x, tid = threadIdx.x;
    __shared__ float hS[256], lgS[256];
    __shared__ float red[8];
    {
        float hold = hbuf[(size_t)b * HID + tid];
        const float* gi = gbuf + (size_t)b * 768;
        const float* gh = gbuf + (size_t)128 * 768 + (size_t)b * 768;
        float r_ = fast_sigm(gi[tid] + bih[tid] + gh[tid] + bhh[tid]);
        float z_ = fast_sigm(gi[256 + tid] + bih[256 + tid] + gh[256 + tid] + bhh[256 + tid]);
        float n_ = fast_tanh(gi[512 + tid] + bih[512 + tid] + r_ * (gh[512 + tid] + bhh[512 + tid]));
        hS[tid] = (1.f - z_) * n_ + z_ * hold;
    }
    __syncthreads();
    float lg = -1e30f;
    if (tid < NC) {
        float a = out_b[tid];
        const u16x8* wp = reinterpret_cast<const u16x8*>(ow_bf + (size_t)tid * 256);
        #pragma unroll 4
        for (int c8 = 0; c8 < 32; c8++) {
            u16x8 u = wp[c8];
            #pragma unroll
            for (int j = 0; j < 8; j++) a += bf2f(u[j]) * hS[c8 * 8 + j];
        }
        lg = a;
    }
    lgS[tid] = lg;
    float m = wave_red_max(lg);
    if ((tid & 63) == 0) red[tid >> 6] = m;
    __syncthreads();
    float M = fmaxf(fmaxf(red[0], red[1]), fmaxf(red[2], red[3]));
    __syncthreads();
    float e = (tid < NC) ? __expf(lg - M) : 0.f;
    float sm = wave_red_sum(e);
    if ((tid & 63) == 0) red[tid >> 6] = sm;
    __syncthreads();
    float S = red[0] + red[1] + red[2] + red[3];
    if (tid == 0) {
        int tgt = word_tgt[b * T + (T - 1)];
        if (tgt >= 0) nll[b] += M + __logf(S) - lgS[tgt];
    }
}

// ---------------- loss ----------------
__global__ void k_reduce(const float* __restrict__ nll, float* __restrict__ out) {
    __shared__ float red[2];
    float v = nll[threadIdx.x];
    v = wave_red_sum(v);
    if ((threadIdx.x & 63) == 0) red[threadIdx.x >> 6] = v;
    __syncthreads();
    if (threadIdx.x == 0) out[0] = 0.2f * (red[0] + red[1]) * (1.f / 128.f);
}

extern "C" void kernel_launch(void* const* d_in, const int* in_sizes, int n_in,
                              void* d_out, int out_size, void* d_ws, size_t ws_size,
                              hipStream_t stream) {
    const float* x        = (const float*)d_in[0];
    const int*   dec_tgt  = (const int*)d_in[1];
    const int*   word_tgt = (const int*)d_in[2];
    const float* conv_w   = (const float*)d_in[3];
    const float* conv_b   = (const float*)d_in[4];
    const float* emb_dec  = (const float*)d_in[5];
    const float* word_w   = (const float*)d_in[6];
    const float* word_b   = (const float*)d_in[7];
    const float* attn_w   = (const float*)d_in[8];
    const float* attn_b   = (const float*)d_in[9];
    const float* attn_v   = (const float*)d_in[10];
    const float* gru_wih  = (const float*)d_in[11];
    const float* gru_bih  = (const float*)d_in[12];
    const float* gru_whh  = (const float*)d_in[13];
    const float* gru_bhh  = (const float*)d_in[14];
    const float* out_w    = (const float*)d_in[15];
    const float* out_b    = (const float*)d_in[16];
    const float* x_emb    = (const float*)d_in[17];
    const float* y_emb    = (const float*)d_in[18];

    char* ws = (char*)d_ws;
    size_t off = 0;
    auto alloc = [&](size_t bytes) -> void* {
        void* p = ws + off;
        off = (off + bytes + 255) & ~(size_t)255;
        return p;
    };
    unsigned short* Xt     = (unsigned short*)alloc((size_t)B * 16 * 64 * 256 * 2);  // 67MB
    unsigned short* enc_bf = (unsigned short*)alloc((size_t)B * L * CENC * 2);        // 19.4MB
    unsigned short* Wt     = (unsigned short*)alloc((size_t)9 * 256 * 256 * 2);
    unsigned short* E_bf   = (unsigned short*)alloc((size_t)NC * HID * 2);
    unsigned short* wA_bf  = (unsigned short*)alloc((size_t)HID * HID * 2);
    unsigned short* ow_bf  = (unsigned short*)alloc((size_t)NC * HID * 2);
    unsigned short* Wg1    = (unsigned short*)alloc((size_t)768 * 576 * 2);
    unsigned short* Wg2    = (unsigned short*)alloc((size_t)768 * 256 * 2);
    float* pos2   = (float*)alloc((size_t)L * 40 * 4);
    unsigned short* rin    = (unsigned short*)alloc((size_t)B * RINW * 2);
    float* gbuf   = (float*)alloc((size_t)2 * B * 768 * 4);
    float* hbuf   = (float*)alloc((size_t)B * HID * 4);
    float* nll    = (float*)alloc((size_t)B * 4);
    // ep_t / enc_t alias Xt (dead after k_convmm)
    unsigned short* ep_t  = Xt;
    unsigned short* enc_t = Xt + (size_t)B * L * HID;
    float* out    = (float*)d_out;

    hipLaunchKernelGGL(k_init, dim3(128), dim3(256), 0, stream, hbuf, nll, rin);
    hipLaunchKernelGGL(k_upsxt, dim3(16, 128), dim3(256), 0, stream, x, Xt);
    hipLaunchKernelGGL(k_wt, dim3(2304), dim3(256), 0, stream, conv_w, Wt);
    hipLaunchKernelGGL(k_encpos, dim3(128), dim3(256), 0, stream, x_emb, y_emb, enc_bf, pos2);
    hipLaunchKernelGGL(k_convmm, dim3(1024, 2), dim3(256), 0, stream, Xt, Wt, conv_b, enc_bf);
    hipLaunchKernelGGL(k_etab, dim3(163), dim3(256), 0, stream, emb_dec, word_w, word_b, E_bf);
    hipLaunchKernelGGL(k_prep, dim3(256), dim3(256), 0, stream, attn_w, out_w, wA_bf, ow_bf);
    hipLaunchKernelGGL(k_wg, dim3(768), dim3(576), 0, stream, gru_wih, gru_whh, Wg1, Wg2);
    hipLaunchKernelGGL(k_ep, dim3(2, 8, 128), dim3(256), 0, stream, enc_bf, attn_w, ep_t);
    hipLaunchKernelGGL(k_enct, dim3(4, 128), dim3(256), 0, stream, enc_bf, enc_t);
    for (int t = 0; t < T; t++) {
        hipLaunchKernelGGL(k_stepA, dim3(128), dim3(1024), 0, stream, t,
                           hbuf, gbuf, gru_bih, gru_bhh, ep_t, enc_t, wA_bf, attn_b,
                           attn_v, ow_bf, out_b, dec_tgt, word_tgt, E_bf, pos2, rin, nll);
        hipLaunchKernelGGL(k_stepB, dim3(12), dim3(256), 0, stream, rin, Wg1, Wg2, gbuf);
    }
    hipLaunchKernelGGL(k_finalnll, dim3(128), dim3(256), 0, stream,
                       hbuf, gbuf, gru_bih, gru_bhh, ow_bf, out_b, word_tgt, nll);
    hipLaunchKernelGGL(k_reduce, dim3(1), dim3(128), 0, stream, nll, out);
}